// Round 7
// baseline (258.322 us; speedup 1.0000x reference)
//
#include <hip/hip_runtime.h>
#include <hip/hip_bf16.h>
#include <stdint.h>
#include <math.h>

#define BB 2
#define CC 512
#define HH 64
#define WW 64
#define LL 4096
#define DD 256
#define CIN 4608   // 512*9
#define NT 144     // K steps of 32

typedef _Float16 half_t;
typedef __attribute__((ext_vector_type(8))) _Float16 f16x8;
typedef __attribute__((ext_vector_type(4))) _Float16 f16x4;
typedef __attribute__((ext_vector_type(4))) float f32x4;

// ---------------- Kernel 0: repack W into per-K-step DMA tiles, pre-swizzled.
__global__ __launch_bounds__(256) void splitW2(const float* __restrict__ W,
                                               char* __restrict__ Wst) {
    int i = blockIdx.x * 256 + threadIdx.x;   // NT*DD*4 = 147456 threads
    if (i >= NT * DD * 4) return;
    int it = i >> 10;                          // per it: 256 d * 4 fs
    int r  = i & 1023;
    int d  = r >> 2;
    int fs = r & 3;
    const float* src = W + (size_t)d * CIN + it * 32 + fs * 8;
    f16x8 h8, l8;
#pragma unroll
    for (int j = 0; j < 8; j++) {
        float w = src[j];
        half_t h = (half_t)w;
        h8[j] = h;
        l8[j] = (half_t)(w - (float)h);
    }
    size_t base = (size_t)it * 32768 + d * 128;
    int sw = (d & 7) << 4;
    *(f16x8*)(Wst + base + ((fs * 16) ^ sw)) = h8;
    *(f16x8*)(Wst + base + ((64 + fs * 16) ^ sw)) = l8;
}

// B LDS row: 64 halves (32 hi | 32 lo) = 128B, 8 slots of 16B, XOR swizzle by (row&7)
__device__ __forceinline__ half_t* ldsAddr(half_t* base, int r, int slot) {
    return base + r * 64 + ((slot ^ (r & 7)) << 3);
}

// gates: counted vmcnt (keep youngest 4 B-image loads in flight), drain LDS, barrier
#define GATE4() do { asm volatile("s_waitcnt vmcnt(4) lgkmcnt(0)" ::: "memory"); \
                     __builtin_amdgcn_s_barrier(); \
                     __builtin_amdgcn_sched_barrier(0); } while (0)
#define GATE0() do { asm volatile("s_waitcnt vmcnt(0) lgkmcnt(0)" ::: "memory"); \
                     __builtin_amdgcn_s_barrier(); \
                     __builtin_amdgcn_sched_barrier(0); } while (0)

// ---------------- Kernel 1: embed via f16 split-3 MFMA + fused D-norm
// C[256 d][64 l] per block; 8 waves (wave 64d x 32l); grid (64 rows, 4 images)
// = 256 blocks, 1/CU. W DMA'd global->LDS (counted vmcnt); unfold staging scalarized.
__global__ __launch_bounds__(512, 1) void embed_mfma(const float* __restrict__ query,
                                                     const float* __restrict__ key,
                                                     const char* __restrict__ Wst,
                                                     char* __restrict__ qemb,
                                                     char* __restrict__ kemb) {
    __shared__ half_t sW[2][16384];     // 64 KB: W tiles swizzled
    __shared__ half_t sB[2][4096];      // 16 KB: unfold tiles (64 rows x 128B)
    __shared__ float red[4][64];
    __shared__ float invn[64];

    int iid = blockIdx.y;               // 0..3
    int b = iid & 1, type = iid >> 1;   // 0=query, 1=key
    const char* imgB = (const char*)((type ? key : query) + (size_t)b * CC * LL);
    int y  = blockIdx.x;                // image row 0..63
    int l0 = y * 64;
    int t = threadIdx.x;
    int w = t >> 6;                     // wave 0..7
    int lane = t & 63;
    int wr = w >> 1;                    // d base wr*64
    int wc = w & 1;                     // l base wc*32
    int fr = lane & 15;
    int fs = lane >> 4;

    // ---- B staging: thread stages 4 k-values for pixel xB; kcB is WAVE-UNIFORM
    int xB = t & 63;
    int kcB = __builtin_amdgcn_readfirstlane(t >> 6);   // 0..7 (scalar)
    int cS = (kcB * 4) / 9;            // scalar state
    int offS = (kcB * 4) % 9;          // scalar state

    // scalar per-di row byte-offsets (row stride WW*4 = 256B) + validity
    int row0 = (y > 0 ? y - 1 : 0) * 256;  int vy0 = (y > 0);
    int row1 = y * 256;
    int row2 = (y < 63 ? y + 1 : 63) * 256; int vy2 = (y < 63);
    // per-lane x byte-offsets per dj + validity
    int X0 = (xB > 0 ? xB - 1 : 0) * 4;    int vx0 = (xB > 0);
    int X1 = xB * 4;
    int X2 = (xB < 63 ? xB + 1 : 63) * 4;  int vx2 = (xB < 63);

    f32x4 acc[4][2];
#pragma unroll
    for (int rg = 0; rg < 4; rg++)
#pragma unroll
        for (int cg = 0; cg < 2; cg++) acc[rg][cg] = (f32x4){0.f, 0.f, 0.f, 0.f};

    float Bv[4];

#define LOADB()                                                          \
    do {                                                                 \
        int cj = cS, oj = offS;                                          \
        _Pragma("unroll")                                                \
        for (int j = 0; j < 4; j++) {                                    \
            int di = (oj >= 6) ? 2 : (oj >= 3) ? 1 : 0;                  \
            int dj = oj - di * 3;                                        \
            int rowb = (di == 0) ? row0 : (di == 1) ? row1 : row2;       \
            int vy   = (di == 0) ? vy0 : (di == 1) ? 1 : vy2;            \
            int xoff = (dj == 0) ? X0 : (dj == 1) ? X1 : X2;             \
            int vx   = (dj == 0) ? vx0 : (dj == 1) ? 1 : vx2;            \
            float v = *(const float*)(imgB + (((size_t)cj) << 14) + rowb + xoff); \
            Bv[j] = (vy & vx) ? v : 0.f;                                 \
            oj++; if (oj >= 9) { oj = 0; cj++; }                         \
        }                                                                \
        cS += 3; offS += 5; if (offS >= 9) { offS -= 9; cS++; }          \
    } while (0)

#define WRITEB(buf)                                                      \
    do {                                                                 \
        f16x4 h4, l4;                                                    \
        _Pragma("unroll")                                                \
        for (int j = 0; j < 4; j++) {                                    \
            half_t h = (half_t)Bv[j];                                    \
            h4[j] = h; l4[j] = (half_t)(Bv[j] - (float)h);               \
        }                                                                \
        *(f16x4*)(ldsAddr(buf, xB, kcB >> 1) + ((kcB & 1) << 2)) = h4;   \
        *(f16x4*)(ldsAddr(buf, xB, 4 + (kcB >> 1)) + ((kcB & 1) << 2)) = l4; \
    } while (0)

    // 512 threads DMA the 32KB W tile: 4 chunks x (512 x 16B)
#define DMAW(swbuf, itv)                                                 \
    do {                                                                 \
        const char* gsrc_ = Wst + (size_t)(itv) * 32768 + t * 16;        \
        char* ldst_ = (char*)(swbuf) + t * 16;                           \
        _Pragma("unroll")                                                \
        for (int c = 0; c < 4; c++)                                      \
            __builtin_amdgcn_global_load_lds(                            \
                (const __attribute__((address_space(1))) void*)(gsrc_ + c * 8192), \
                (__attribute__((address_space(3))) void*)(ldst_ + c * 8192), 16, 0, 0); \
    } while (0)

#define READA(swbuf)                                                     \
    do {                                                                 \
        _Pragma("unroll")                                                \
        for (int rg = 0; rg < 4; rg++) {                                 \
            int dl = wr * 64 + rg * 16 + fr;                             \
            int sw_ = (dl & 7) << 4;                                     \
            const char* rowp = (const char*)(swbuf) + dl * 128;          \
            ah[rg] = *(const f16x8*)(rowp + ((fs * 16) ^ sw_));          \
            al[rg] = *(const f16x8*)(rowp + ((64 + fs * 16) ^ sw_));     \
        }                                                                \
    } while (0)

#define READB(buf)                                                       \
    do {                                                                 \
        _Pragma("unroll")                                                \
        for (int cg = 0; cg < 2; cg++) {                                 \
            int r = wc * 32 + cg * 16 + fr;                              \
            bh[cg] = *(f16x8*)ldsAddr(buf, r, fs);                       \
            bl[cg] = *(f16x8*)ldsAddr(buf, r, fs + 4);                   \
        }                                                                \
    } while (0)

#define DOMFMA()                                                         \
    do {                                                                 \
        _Pragma("unroll")                                                \
        for (int rg = 0; rg < 4; rg++)                                   \
            _Pragma("unroll")                                            \
            for (int cg = 0; cg < 2; cg++)                               \
                acc[rg][cg] = __builtin_amdgcn_mfma_f32_16x16x32_f16(ah[rg], bh[cg], acc[rg][cg], 0, 0, 0); \
        _Pragma("unroll")                                                \
        for (int rg = 0; rg < 4; rg++)                                   \
            _Pragma("unroll")                                            \
            for (int cg = 0; cg < 2; cg++) {                             \
                acc[rg][cg] = __builtin_amdgcn_mfma_f32_16x16x32_f16(ah[rg], bl[cg], acc[rg][cg], 0, 0, 0); \
                acc[rg][cg] = __builtin_amdgcn_mfma_f32_16x16x32_f16(al[rg], bh[cg], acc[rg][cg], 0, 0, 0); \
            }                                                            \
    } while (0)

    f16x8 ah[4], al[4], bh[2], bl[2];

    LOADB();
    DMAW(&sW[0][0], 0);
    __builtin_amdgcn_sched_barrier(0);
    WRITEB(&sB[0][0]);
    __builtin_amdgcn_sched_barrier(0);
    LOADB();

    half_t* swc = &sW[0][0]; half_t* swn = &sW[1][0];
    half_t* sbc = &sB[0][0]; half_t* sbn = &sB[1][0];

    for (int it = 0; it < NT - 1; ++it) {
        GATE4();
        READA(swc);
        READB(sbc);
        WRITEB(sbn);
        __builtin_amdgcn_sched_barrier(0);
        DMAW(swn, it + 1);
        __builtin_amdgcn_sched_barrier(0);
        if (it < NT - 2) LOADB();
        DOMFMA();
        half_t* tp = swc; swc = swn; swn = tp;
        tp = sbc; sbc = sbn; sbn = tp;
    }
    GATE0();
    READA(swc);
    READB(sbc);
    DOMFMA();

    // ---- fused normalization over d (full 256 within block)
    float ss[2] = {0.f, 0.f};
#pragma unroll
    for (int rg = 0; rg < 4; rg++)
#pragma unroll
        for (int cg = 0; cg < 2; cg++)
#pragma unroll
            for (int r = 0; r < 4; r++) ss[cg] += acc[rg][cg][r] * acc[rg][cg][r];
#pragma unroll
    for (int cg = 0; cg < 2; cg++) {
        ss[cg] += __shfl_xor(ss[cg], 16);
        ss[cg] += __shfl_xor(ss[cg], 32);
    }
    if (lane < 16) {
        red[wr][wc * 32 + lane] = ss[0];
        red[wr][wc * 32 + 16 + lane] = ss[1];
    }
    __syncthreads();
    if (t < 64) {
        float s = red[0][t] + red[1][t] + red[2][t] + red[3][t];
        invn[t] = 1.0f / fmaxf(sqrtf(s), 1e-12f);
    }
    __syncthreads();

    // ---- epilogue: corr-ready swizzled layout
    char* e = (type == 0) ? qemb : kemb;
#pragma unroll
    for (int cg = 0; cg < 2; cg++) {
        int lloc = wc * 32 + cg * 16 + fr;
        float sc = invn[lloc];
        int l = l0 + lloc;
        char* rowp = e + ((size_t)b * LL + l) * 1024;
        int swb = (l & 7) << 4;
#pragma unroll
        for (int rg = 0; rg < 4; rg++) {
            int d0 = wr * 64 + rg * 16 + fs * 4;
            f16x4 h4, l4;
#pragma unroll
            for (int r = 0; r < 4; r++) {
                float v = acc[rg][cg][r] * sc;
                half_t h = (half_t)v;
                h4[r] = h;
                l4[r] = (half_t)(v - (float)h);
            }
            int itb = d0 >> 5;
            int fsc = (d0 >> 3) & 3;
            int sub = (d0 & 7) * 2;
            *(f16x4*)(rowp + itb * 128 + ((fsc * 16) ^ swb) + sub) = h4;
            *(f16x4*)(rowp + itb * 128 + ((64 + fsc * 16) ^ swb) + sub) = l4;
        }
    }
#undef LOADB
#undef WRITEB
#undef DMAW
#undef READA
#undef READB
#undef DOMFMA
}

// ---------------- Kernel 2: init packed max buffer
__global__ void init_packed(unsigned long long* p, int n) {
    int i = blockIdx.x * 256 + threadIdx.x;
    if (i < n) p[i] = 0ull;
}

// ---------------- Kernel 3: corr via LDS-staged split-3 MFMA + fused max/argmax
// 128l x 128m tile per block; 4 waves (64l x 64m each); K=256 in 8 steps, dbuf DMA.
__global__ __launch_bounds__(256, 2) void corr_max_mfma(const char* __restrict__ kemb,
                                                        const char* __restrict__ qemb,
                                                        unsigned long long* __restrict__ packed) {
    __shared__ char sA[2][16384];
    __shared__ char sBq[2][16384];

    int b  = blockIdx.z;
    int l0 = blockIdx.y * 128;
    int m0 = blockIdx.x * 128;
    int t  = threadIdx.x;
    int w = t >> 6, lane = t & 63;
    int wr = w >> 1, wc = w & 1;        // wave: l base wr*64, m base wc*64
    int fr = lane & 15, fs = lane >> 4;

    const char* Abase = kemb + ((size_t)b * LL + l0) * 1024;
    const char* Bbase = qemb + ((size_t)b * LL + m0) * 1024;

    f32x4 acc[4][4];
#pragma unroll
    for (int i = 0; i < 4; i++)
#pragma unroll
        for (int j = 0; j < 4; j++) acc[i][j] = (f32x4){0.f, 0.f, 0.f, 0.f};

#define DMA2(bufi, itv)                                                   \
    do {                                                                  \
        _Pragma("unroll")                                                 \
        for (int c = 0; c < 4; c++) {                                     \
            int idx = c * 4096 + t * 16;                                  \
            int row = idx >> 7, offb = idx & 127;                         \
            __builtin_amdgcn_global_load_lds(                             \
                (const __attribute__((address_space(1))) void*)(Abase + (size_t)row * 1024 + (itv) * 128 + offb), \
                (__attribute__((address_space(3))) void*)(&sA[bufi][idx]), 16, 0, 0); \
        }                                                                 \
        _Pragma("unroll")                                                 \
        for (int c = 0; c < 4; c++) {                                     \
            int idx = c * 4096 + t * 16;                                  \
            int row = idx >> 7, offb = idx & 127;                         \
            __builtin_amdgcn_global_load_lds(                             \
                (const __attribute__((address_space(1))) void*)(Bbase + (size_t)row * 1024 + (itv) * 128 + offb), \
                (__attribute__((address_space(3))) void*)(&sBq[bufi][idx]), 16, 0, 0); \
        }                                                                 \
    } while (0)

    DMA2(0, 0);

    f16x8 ah[4], al[4], bh[4], bl[4];
    for (int it = 0; it < 8; ++it) {
        asm volatile("s_waitcnt vmcnt(0) lgkmcnt(0)" ::: "memory");
        __builtin_amdgcn_s_barrier();
        __builtin_amdgcn_sched_barrier(0);
        if (it < 7) DMA2((it + 1) & 1, it + 1);
        __builtin_amdgcn_sched_barrier(0);
        const char* sa = sA[it & 1];
        const char* sb = sBq[it & 1];
#pragma unroll
        for (int rg = 0; rg < 4; rg++) {
            int r = wr * 64 + rg * 16 + fr;
            const char* rp = sa + r * 128;
            int sw_ = (r & 7) << 4;
            ah[rg] = *(const f16x8*)(rp + ((fs * 16) ^ sw_));
            al[rg] = *(const f16x8*)(rp + ((64 + fs * 16) ^ sw_));
        }
#pragma unroll
        for (int cg = 0; cg < 4; cg++) {
            int r = wc * 64 + cg * 16 + fr;
            const char* rp = sb + r * 128;
            int sw_ = (r & 7) << 4;
            bh[cg] = *(const f16x8*)(rp + ((fs * 16) ^ sw_));
            bl[cg] = *(const f16x8*)(rp + ((64 + fs * 16) ^ sw_));
        }
#pragma unroll
        for (int rg = 0; rg < 4; rg++)
#pragma unroll
            for (int cg = 0; cg < 4; cg++)
                acc[rg][cg] = __builtin_amdgcn_mfma_f32_16x16x32_f16(ah[rg], bh[cg], acc[rg][cg], 0, 0, 0);
#pragma unroll
        for (int rg = 0; rg < 4; rg++)
#pragma unroll
            for (int cg = 0; cg < 4; cg++) {
                acc[rg][cg] = __builtin_amdgcn_mfma_f32_16x16x32_f16(ah[rg], bl[cg], acc[rg][cg], 0, 0, 0);
                acc[rg][cg] = __builtin_amdgcn_mfma_f32_16x16x32_f16(al[rg], bh[cg], acc[rg][cg], 0, 0, 0);
            }
    }
#undef DMA2

    // column max per m (C: col m = fr, row l = fs*4+r)
#pragma unroll
    for (int cg = 0; cg < 4; cg++) {
        unsigned long long best = 0ull;
#pragma unroll
        for (int rg = 0; rg < 4; rg++) {
#pragma unroll
            for (int r = 0; r < 4; r++) {
                unsigned u = __float_as_uint(acc[rg][cg][r]);
                u = (u & 0x80000000u) ? ~u : (u | 0x80000000u);
                int l = l0 + wr * 64 + rg * 16 + fs * 4 + r;
                unsigned long long p = ((unsigned long long)u << 32) | (unsigned)(4095 - l);
                best = (p > best) ? p : best;
            }
        }
        unsigned long long o;
        o = __shfl_xor(best, 16); best = (o > best) ? o : best;
        o = __shfl_xor(best, 32); best = (o > best) ? o : best;
        if (lane < 16)
            atomicMax(&packed[(size_t)b * LL + m0 + wc * 64 + cg * 16 + lane], best);
    }
}

// ---------------- Kernel 4: decode packed -> S (d_out) + argmax (ws)
__global__ void decode_packed(const unsigned long long* __restrict__ packed,
                              float* __restrict__ S_out, int* __restrict__ arg) {
    int i = blockIdx.x * 256 + threadIdx.x;
    if (i < BB * LL) {
        unsigned long long p = packed[i];
        unsigned u = (unsigned)(p >> 32);
        unsigned bits = (u & 0x80000000u) ? (u & 0x7FFFFFFFu) : ~u;
        S_out[i] = __uint_as_float(bits);
        arg[i] = 4095 - (int)(unsigned)(p & 0xFFFFFFFFull);
    }
}

// ---------------- Kernel 5/7: batched 2D transpose src[R][Cc] -> dst[Cc][R]
__global__ __launch_bounds__(256) void transpose_mat(const float* __restrict__ src,
                                                     float* __restrict__ dst,
                                                     int R, int Cc) {
    __shared__ float tile[32][33];
    size_t boff = (size_t)blockIdx.z * R * Cc;
    int bx = blockIdx.x;
    int by = blockIdx.y;
    int tx = threadIdx.x & 31;
    int ty = threadIdx.x >> 5;
    const float* s = src + boff;
    float* d = dst + boff;
#pragma unroll
    for (int i = 0; i < 4; i++) {
        int r = by * 32 + ty + i * 8;
        int c = bx * 32 + tx;
        tile[ty + i * 8][tx] = s[(size_t)r * Cc + c];
    }
    __syncthreads();
#pragma unroll
    for (int i = 0; i < 4; i++) {
        int c = bx * 32 + ty + i * 8;
        int r = by * 32 + tx;
        d[(size_t)c * R + r] = tile[tx][ty + i * 8];
    }
}

// ---------------- Kernel 6: gather + fold (channel-last), one pixel per block
__global__ __launch_bounds__(256) void gather_fold(const float* __restrict__ value_t,
                                                   const int* __restrict__ arg,
                                                   float* __restrict__ T_t) {
    int b = blockIdx.y;
    int pix = blockIdx.x;
    int y = pix >> 6, x = pix & 63;
    int t = threadIdx.x;
    float2 acc = make_float2(0.f, 0.f);
    int cnty = (y == 0 || y == HH - 1) ? 2 : 3;
    int cntx = (x == 0 || x == WW - 1) ? 2 : 3;
    const int* ab = arg + b * LL;
    const float* vb = value_t + (size_t)b * LL * CC;
#pragma unroll
    for (int di = 0; di < 3; di++) {
        int my = y + 1 - di;
        if (my < 0 || my >= HH) continue;
#pragma unroll
        for (int dj = 0; dj < 3; dj++) {
            int mx = x + 1 - dj;
            if (mx < 0 || mx >= WW) continue;
            int a = ab[my * WW + mx];
            int ay = a >> 6, ax = a & 63;
            int vy = ay + di - 1, vx = ax + dj - 1;
            if (vy < 0 || vy >= HH || vx < 0 || vx >= WW) continue;
            float2 v = *(const float2*)&vb[((size_t)(vy * WW + vx)) * CC + t * 2];
            acc.x += v.x; acc.y += v.y;
        }
    }
    float inv = 1.0f / (float)(cnty * cntx);
    acc.x *= inv; acc.y *= inv;
    *(float2*)&T_t[((size_t)b * LL + pix) * CC + t * 2] = acc;
}

extern "C" void kernel_launch(void* const* d_in, const int* in_sizes, int n_in,
                              void* d_out, int out_size, void* d_ws, size_t ws_size,
                              hipStream_t stream) {
    const float* query = (const float*)d_in[0];
    const float* key   = (const float*)d_in[1];
    const float* value = (const float*)d_in[2];
    const float* Wemb  = (const float*)d_in[3];

    float* out   = (float*)d_out;
    float* S_out = out;
    float* T_out = out + BB * LL;

    char* ws = (char*)d_ws;
    size_t off = 0;
    char* Wst  = ws + off; off += (size_t)NT * 32768;                 // 4.72 MB (dead after embed)
    char* qemb = ws + off; off += (size_t)BB * LL * 1024;             // 8.39 MB (dead after corr)
    char* kemb = ws + off; off += (size_t)BB * LL * 1024;             // 8.39 MB (dead after corr)
    float* val_t = (float*)(ws + off); off += (size_t)BB * LL * CC * 4;  // 16.78 MB
    unsigned long long* packed = (unsigned long long*)(ws + off); off += (size_t)BB * LL * 8;
    int* arg = (int*)(ws + off); off += (size_t)BB * LL * 4;
    float* T_t = (float*)ws;  // alias Wst+qemb+part of kemb (all dead by then)

    splitW2       <<<dim3(576), 256, 0, stream>>>(Wemb, Wst);
    embed_mfma    <<<dim3(64, 4), 512, 0, stream>>>(query, key, Wst, qemb, kemb);
    init_packed   <<<dim3(32), 256, 0, stream>>>(packed, BB * LL);
    corr_max_mfma <<<dim3(32, 32, 2), 256, 0, stream>>>(kemb, qemb, packed);
    decode_packed <<<dim3(32), 256, 0, stream>>>(packed, S_out, arg);
    transpose_mat <<<dim3(128, 16, 2), 256, 0, stream>>>(value, val_t, CC, LL);
    gather_fold   <<<dim3(4096, 2), 256, 0, stream>>>(val_t, arg, T_t);
    transpose_mat <<<dim3(16, 128, 2), 256, 0, stream>>>(T_t, T_out, LL, CC);
}

// Round 9
// 229.284 us; speedup vs baseline: 1.1266x; 1.1266x over previous
//
#include <hip/hip_runtime.h>
#include <hip/hip_bf16.h>
#include <stdint.h>
#include <math.h>

#define BB 2
#define CC 512
#define HH 64
#define WW 64
#define LL 4096
#define DD 256
#define CIN 4608   // 512*9
#define NG 144     // gates = 16 c-chunks x 9 offsets

typedef _Float16 half_t;
typedef __attribute__((ext_vector_type(8))) _Float16 f16x8;
typedef __attribute__((ext_vector_type(4))) _Float16 f16x4;
typedef __attribute__((ext_vector_type(4))) float f32x4;

// ---------------- Kernel A: presplit images -> channel-last f16 hi/lo, swizzled
// img_ts layout: [img 4][y 64][cc 16][x 64][128B]; within 128B, phys 16B slot p
// holds logical slot (p ^ (x&7)); logical slot L = half*4+fs covers channels
// c = cc*32 + fs*8 .. +7 (half 0 = hi, half 1 = lo residual).
__global__ __launch_bounds__(256) void presplit(const float* __restrict__ query,
                                                const float* __restrict__ key,
                                                char* __restrict__ img_ts) {
    __shared__ float tile[32][65];
    int img = blockIdx.y;               // b = img&1, type = img>>1
    int y   = blockIdx.x;
    const float* src = ((img >> 1) ? key : query) + (size_t)(img & 1) * CC * LL + y * WW;
    char* dstbase = img_ts + ((size_t)img * 64 + y) * (16 * 64 * 128);
    int t = threadIdx.x;
    int xl = t & 63, c4 = t >> 6;
    int xw = t >> 2, fsw = t & 3;
    for (int cc = 0; cc < 16; ++cc) {
#pragma unroll
        for (int j = 0; j < 8; ++j) {
            int cl = c4 + j * 4;
            tile[cl][xl] = src[(size_t)(cc * 32 + cl) * LL + xl];
        }
        __syncthreads();
        f16x8 h8, l8;
#pragma unroll
        for (int j = 0; j < 8; ++j) {
            float v = tile[fsw * 8 + j][xw];
            half_t h = (half_t)v;
            h8[j] = h; l8[j] = (half_t)(v - (float)h);
        }
        char* p = dstbase + (size_t)cc * 8192 + xw * 128;
        int swz = (xw & 7) << 4;
        *(f16x8*)(p + ((fsw * 16) ^ swz)) = h8;
        *(f16x8*)(p + ((64 + fsw * 16) ^ swz)) = l8;
        __syncthreads();
    }
}

// ---------------- Kernel B: repack W into per-gate tiles [g = cc*9+o][d][128B]
// A-frag element j (of fs-slot): W[d][(cc*32+fs*8+j)*9 + o], swizzled by (d&7).
__global__ __launch_bounds__(256) void splitW2b(const float* __restrict__ W,
                                                char* __restrict__ Wst) {
    int i = blockIdx.x * 256 + threadIdx.x;   // NG*DD*4 = 147456
    if (i >= NG * DD * 4) return;
    int g  = i >> 10;
    int r  = i & 1023;
    int d  = r >> 2;
    int fs = r & 3;
    int cc = g / 9, o = g - cc * 9;
    const float* src = W + (size_t)d * CIN;
    f16x8 h8, l8;
#pragma unroll
    for (int j = 0; j < 8; j++) {
        float w = src[(cc * 32 + fs * 8 + j) * 9 + o];
        half_t h = (half_t)w;
        h8[j] = h;
        l8[j] = (half_t)(w - (float)h);
    }
    size_t base = (size_t)g * 32768 + d * 128;
    int sw = (d & 7) << 4;
    *(f16x8*)(Wst + base + ((fs * 16) ^ sw)) = h8;
    *(f16x8*)(Wst + base + ((64 + fs * 16) ^ sw)) = l8;
}

#define GATE() do { asm volatile("s_waitcnt vmcnt(0) lgkmcnt(0)" ::: "memory"); \
                    __builtin_amdgcn_s_barrier(); \
                    __builtin_amdgcn_sched_barrier(0); } while (0)

// ---------------- Kernel 1: embed, offset-decomposed implicit-conv GEMM.
// Block: 256d x 64l (one image row), 8 waves (64d x 32l). 144 gates of (cc,o):
// pure-DMA staging (W per gate, B per chunk reused by 9 offsets), register
// fragment double-buffer pipelines ds_read(g) under MFMA(g-1).
__global__ __launch_bounds__(512) void embed_mfma(const char* __restrict__ img_ts,
                                                  const char* __restrict__ Wst,
                                                  const char* __restrict__ zp,
                                                  char* __restrict__ qemb,
                                                  char* __restrict__ kemb) {
    __shared__ char sW[2][32768];       // W tiles
    __shared__ char sB[2][32768];       // B tiles: [di 3][xi 66][128B] + pad
    __shared__ float red[4][64];
    __shared__ float invn[64];

    int iid = blockIdx.y;               // 0..3
    int b = iid & 1, type = iid >> 1;
    int y = blockIdx.x;                 // image row
    int l0 = y * 64;
    int t = threadIdx.x;
    int w = t >> 6, lane = t & 63;
    int wr = w >> 1, wc = w & 1;        // wave: d base wr*64, l base wc*32
    int fr = lane & 15, fs = lane >> 4;

    // ---- per-thread B-DMA source precompute (4 calls of 16B per thread)
    // img_ts is ALREADY phys-swizzled; DMA must copy phys->phys LINEARLY
    // (rule #21: linear dest + pre-swizzled global + swizzle on ds_read).
    const char* imgb = img_ts + (size_t)iid * (64 * 16 * 64 * 128);
    const char *ps0, *ps1, *ps2, *ps3;
    int pb0, pb1, pb2, pb3;             // per-chunk bump (8192 or 0)
#define PREP(c, PS, PB)                                                 \
    {                                                                   \
        int q = (c) * 512 + t;                                          \
        int di = q / 528;                                               \
        int rem = q - di * 528;                                         \
        int xi = rem >> 3, sub = rem & 7;                               \
        int xg = xi - 1, yg = y + di - 1;                               \
        bool ok = (di < 3) && (yg >= 0) && (yg < 64) && (xg >= 0) && (xg < 64); \
        PS = ok ? imgb + (size_t)yg * 131072 + (size_t)xg * 128 + (sub * 16) \
                : zp + ((q & 255) * 16);                                \
        PB = ok ? 8192 : 0;                                             \
    }
    PREP(0, ps0, pb0); PREP(1, ps1, pb1); PREP(2, ps2, pb2); PREP(3, ps3, pb3);

    const char* pW = Wst;

#define DMAW(dst)                                                       \
    do {                                                                \
        _Pragma("unroll")                                               \
        for (int c = 0; c < 4; c++)                                     \
            __builtin_amdgcn_global_load_lds(                           \
                (const __attribute__((address_space(1))) void*)(pW + c * 8192 + t * 16), \
                (__attribute__((address_space(3))) void*)((dst) + c * 8192 + t * 16), 16, 0, 0); \
        pW += 32768;                                                    \
    } while (0)

#define DMAB(dst)                                                       \
    do {                                                                \
        __builtin_amdgcn_global_load_lds((const __attribute__((address_space(1))) void*)ps0, \
            (__attribute__((address_space(3))) void*)((dst) + t * 16), 16, 0, 0); \
        __builtin_amdgcn_global_load_lds((const __attribute__((address_space(1))) void*)ps1, \
            (__attribute__((address_space(3))) void*)((dst) + 8192 + t * 16), 16, 0, 0); \
        __builtin_amdgcn_global_load_lds((const __attribute__((address_space(1))) void*)ps2, \
            (__attribute__((address_space(3))) void*)((dst) + 16384 + t * 16), 16, 0, 0); \
        __builtin_amdgcn_global_load_lds((const __attribute__((address_space(1))) void*)ps3, \
            (__attribute__((address_space(3))) void*)((dst) + 24576 + t * 16), 16, 0, 0); \
        ps0 += pb0; ps1 += pb1; ps2 += pb2; ps3 += pb3;                 \
    } while (0)

#define READA(AH, AL, wbuf)                                             \
    do {                                                                \
        _Pragma("unroll")                                               \
        for (int rg = 0; rg < 4; rg++) {                                \
            int dl = wr * 64 + rg * 16 + fr;                            \
            int sw_ = (dl & 7) << 4;                                    \
            const char* rowp = (const char*)(wbuf) + dl * 128;          \
            AH[rg] = *(const f16x8*)(rowp + ((fs * 16) ^ sw_));         \
            AL[rg] = *(const f16x8*)(rowp + ((64 + fs * 16) ^ sw_));    \
        }                                                               \
    } while (0)

#define READB(BH, BL, bbuf, di_, dj_)                                   \
    do {                                                                \
        _Pragma("unroll")                                               \
        for (int cg = 0; cg < 2; cg++) {                                \
            int xi = wc * 32 + cg * 16 + fr + (dj_);                    \
            int sw_ = ((xi - 1) & 7) << 4;                              \
            const char* rowp = (const char*)(bbuf) + (di_) * 8448 + xi * 128; \
            BH[cg] = *(const f16x8*)(rowp + ((fs * 16) ^ sw_));         \
            BL[cg] = *(const f16x8*)(rowp + ((64 + fs * 16) ^ sw_));    \
        }                                                               \
    } while (0)

#define DOMFMA(AH, AL, BH, BL)                                          \
    do {                                                                \
        _Pragma("unroll")                                               \
        for (int rg = 0; rg < 4; rg++)                                  \
            _Pragma("unroll")                                           \
            for (int cg = 0; cg < 2; cg++)                              \
                acc[rg][cg] = __builtin_amdgcn_mfma_f32_16x16x32_f16(AH[rg], BH[cg], acc[rg][cg], 0, 0, 0); \
        _Pragma("unroll")                                               \
        for (int rg = 0; rg < 4; rg++)                                  \
            _Pragma("unroll")                                           \
            for (int cg = 0; cg < 2; cg++) {                            \
                acc[rg][cg] = __builtin_amdgcn_mfma_f32_16x16x32_f16(AH[rg], BL[cg], acc[rg][cg], 0, 0, 0); \
                acc[rg][cg] = __builtin_amdgcn_mfma_f32_16x16x32_f16(AL[rg], BH[cg], acc[rg][cg], 0, 0, 0); \
            }                                                           \
    } while (0)

    f32x4 acc[4][2];
#pragma unroll
    for (int rg = 0; rg < 4; rg++)
#pragma unroll
        for (int cg = 0; cg < 2; cg++) acc[rg][cg] = (f32x4){0.f, 0.f, 0.f, 0.f};

    f16x8 ah0[4], al0[4], bh0[2], bl0[2];
    f16x8 ah1[4], al1[4], bh1[2], bl1[2];

    char* wb0 = &sW[0][0]; char* wb1 = &sW[1][0];
    char* b0 = &sB[0][0];  char* b1 = &sB[1][0];

    // ---- prologue: B(0), W(0); gate; read g=0; issue W(1), B(1)
    DMAB(b0);
    DMAW(wb0);
    GATE();
    READA(ah0, al0, wb0);
    READB(bh0, bl0, b0, 0, 0);          // g=0: o=0 (di=0,dj=0)
    DMAW(wb1);
    DMAB(b1);
    __builtin_amdgcn_sched_barrier(0);

    int o = 1, issued = 2;
    char* bcur = b0;
    char* bnext = b0;                    // B(2) -> sB[0]

#define HALF(AHr, ALr, BHr, BLr, WRD, WWR, AHm, ALm, BHm, BLm)          \
    GATE();                                                             \
    READA(AHr, ALr, WRD);                                               \
    {                                                                   \
        int di_ = (o >= 6) ? 2 : (o >= 3) ? 1 : 0;                      \
        int dj_ = o - di_ * 3;                                          \
        READB(BHr, BLr, bcur, di_, dj_);                                \
    }                                                                   \
    DMAW(WWR);                                                          \
    if (o == 0 && issued < 16) {                                        \
        DMAB(bnext);                                                    \
        bnext = (bnext == b0) ? b1 : b0;                                \
        issued++;                                                       \
    }                                                                   \
    o++; if (o == 9) { o = 0; bcur = (bcur == b0) ? b1 : b0; }          \
    __builtin_amdgcn_sched_barrier(0);                                  \
    DOMFMA(AHm, ALm, BHm, BLm);

#pragma unroll 1
    for (int i = 0; i < 71; ++i) {
        HALF(ah1, al1, bh1, bl1, wb1, wb0, ah0, al0, bh0, bl0)   // read odd g
        HALF(ah0, al0, bh0, bl0, wb0, wb1, ah1, al1, bh1, bl1)   // read even g
    }
    // ---- tail: read g=143 (o=8: di=2,dj=2), then last two MFMA sets
    GATE();
    READA(ah1, al1, wb1);
    READB(bh1, bl1, bcur, 2, 2);
    __builtin_amdgcn_sched_barrier(0);
    DOMFMA(ah0, al0, bh0, bl0);
    DOMFMA(ah1, al1, bh1, bl1);
#undef HALF

    // ---- fused normalization over d (full 256 within block)
    float ss[2] = {0.f, 0.f};
#pragma unroll
    for (int rg = 0; rg < 4; rg++)
#pragma unroll
        for (int cg = 0; cg < 2; cg++)
#pragma unroll
            for (int r = 0; r < 4; r++) ss[cg] += acc[rg][cg][r] * acc[rg][cg][r];
#pragma unroll
    for (int cg = 0; cg < 2; cg++) {
        ss[cg] += __shfl_xor(ss[cg], 16);
        ss[cg] += __shfl_xor(ss[cg], 32);
    }
    if (lane < 16) {
        red[wr][wc * 32 + lane] = ss[0];
        red[wr][wc * 32 + 16 + lane] = ss[1];
    }
    __syncthreads();
    if (t < 64) {
        float s = red[0][t] + red[1][t] + red[2][t] + red[3][t];
        invn[t] = 1.0f / fmaxf(sqrtf(s), 1e-12f);
    }
    __syncthreads();

    // ---- epilogue: corr-ready swizzled layout
    char* e = (type == 0) ? qemb : kemb;
#pragma unroll
    for (int cg = 0; cg < 2; cg++) {
        int lloc = wc * 32 + cg * 16 + fr;
        float sc = invn[lloc];
        int l = l0 + lloc;
        char* rowp = e + ((size_t)b * LL + l) * 1024;
        int swb = (l & 7) << 4;
#pragma unroll
        for (int rg = 0; rg < 4; rg++) {
            int d0 = wr * 64 + rg * 16 + fs * 4;
            f16x4 h4, l4;
#pragma unroll
            for (int r = 0; r < 4; r++) {
                float v = acc[rg][cg][r] * sc;
                half_t h = (half_t)v;
                h4[r] = h;
                l4[r] = (half_t)(v - (float)h);
            }
            int itb = d0 >> 5;
            int fsc = (d0 >> 3) & 3;
            int sub = (d0 & 7) * 2;
            *(f16x4*)(rowp + itb * 128 + ((fsc * 16) ^ swb) + sub) = h4;
            *(f16x4*)(rowp + itb * 128 + ((64 + fsc * 16) ^ swb) + sub) = l4;
        }
    }
#undef PREP
#undef DMAW
#undef DMAB
#undef READA
#undef READB
#undef DOMFMA
}

// ---------------- Kernel 2: zero init (packed max buffer + zero page)
__global__ void init_packed(unsigned long long* p, int n) {
    int i = blockIdx.x * 256 + threadIdx.x;
    if (i < n) p[i] = 0ull;
}

// ---------------- Kernel 3: corr via LDS-staged split-3 MFMA + fused max/argmax
__global__ __launch_bounds__(256, 2) void corr_max_mfma(const char* __restrict__ kemb,
                                                        const char* __restrict__ qemb,
                                                        unsigned long long* __restrict__ packed) {
    __shared__ char sA[2][16384];
    __shared__ char sBq[2][16384];

    int b  = blockIdx.z;
    int l0 = blockIdx.y * 128;
    int m0 = blockIdx.x * 128;
    int t  = threadIdx.x;
    int w = t >> 6, lane = t & 63;
    int wr = w >> 1, wc = w & 1;
    int fr = lane & 15, fs = lane >> 4;

    const char* Abase = kemb + ((size_t)b * LL + l0) * 1024;
    const char* Bbase = qemb + ((size_t)b * LL + m0) * 1024;

    f32x4 acc[4][4];
#pragma unroll
    for (int i = 0; i < 4; i++)
#pragma unroll
        for (int j = 0; j < 4; j++) acc[i][j] = (f32x4){0.f, 0.f, 0.f, 0.f};

#define DMA2(bufi, itv)                                                   \
    do {                                                                  \
        _Pragma("unroll")                                                 \
        for (int c = 0; c < 4; c++) {                                     \
            int idx = c * 4096 + t * 16;                                  \
            int row = idx >> 7, offb = idx & 127;                         \
            __builtin_amdgcn_global_load_lds(                             \
                (const __attribute__((address_space(1))) void*)(Abase + (size_t)row * 1024 + (itv) * 128 + offb), \
                (__attribute__((address_space(3))) void*)(&sA[bufi][idx]), 16, 0, 0); \
        }                                                                 \
        _Pragma("unroll")                                                 \
        for (int c = 0; c < 4; c++) {                                     \
            int idx = c * 4096 + t * 16;                                  \
            int row = idx >> 7, offb = idx & 127;                         \
            __builtin_amdgcn_global_load_lds(                             \
                (const __attribute__((address_space(1))) void*)(Bbase + (size_t)row * 1024 + (itv) * 128 + offb), \
                (__attribute__((address_space(3))) void*)(&sBq[bufi][idx]), 16, 0, 0); \
        }                                                                 \
    } while (0)

    DMA2(0, 0);

    f16x8 ah[4], al[4], bh[4], bl[4];
    for (int it = 0; it < 8; ++it) {
        asm volatile("s_waitcnt vmcnt(0) lgkmcnt(0)" ::: "memory");
        __builtin_amdgcn_s_barrier();
        __builtin_amdgcn_sched_barrier(0);
        if (it < 7) DMA2((it + 1) & 1, it + 1);
        __builtin_amdgcn_sched_barrier(0);
        const char* sa = sA[it & 1];
        const char* sb = sBq[it & 1];
#pragma unroll
        for (int rg = 0; rg < 4; rg++) {
            int r = wr * 64 + rg * 16 + fr;
            const char* rp = sa + r * 128;
            int sw_ = (r & 7) << 4;
            ah[rg] = *(const f16x8*)(rp + ((fs * 16) ^ sw_));
            al[rg] = *(const f16x8*)(rp + ((64 + fs * 16) ^ sw_));
        }
#pragma unroll
        for (int cg = 0; cg < 4; cg++) {
            int r = wc * 64 + cg * 16 + fr;
            const char* rp = sb + r * 128;
            int sw_ = (r & 7) << 4;
            bh[cg] = *(const f16x8*)(rp + ((fs * 16) ^ sw_));
            bl[cg] = *(const f16x8*)(rp + ((64 + fs * 16) ^ sw_));
        }
#pragma unroll
        for (int rg = 0; rg < 4; rg++)
#pragma unroll
            for (int cg = 0; cg < 4; cg++)
                acc[rg][cg] = __builtin_amdgcn_mfma_f32_16x16x32_f16(ah[rg], bh[cg], acc[rg][cg], 0, 0, 0);
#pragma unroll
        for (int rg = 0; rg < 4; rg++)
#pragma unroll
            for (int cg = 0; cg < 4; cg++) {
                acc[rg][cg] = __builtin_amdgcn_mfma_f32_16x16x32_f16(ah[rg], bl[cg], acc[rg][cg], 0, 0, 0);
                acc[rg][cg] = __builtin_amdgcn_mfma_f32_16x16x32_f16(al[rg], bh[cg], acc[rg][cg], 0, 0, 0);
            }
    }
#undef DMA2

#pragma unroll
    for (int cg = 0; cg < 4; cg++) {
        unsigned long long best = 0ull;
#pragma unroll
        for (int rg = 0; rg < 4; rg++) {
#pragma unroll
            for (int r = 0; r < 4; r++) {
                unsigned u = __float_as_uint(acc[rg][cg][r]);
                u = (u & 0x80000000u) ? ~u : (u | 0x80000000u);
                int l = l0 + wr * 64 + rg * 16 + fs * 4 + r;
                unsigned long long p = ((unsigned long long)u << 32) | (unsigned)(4095 - l);
                best = (p > best) ? p : best;
            }
        }
        unsigned long long oo;
        oo = __shfl_xor(best, 16); best = (oo > best) ? oo : best;
        oo = __shfl_xor(best, 32); best = (oo > best) ? oo : best;
        if (lane < 16)
            atomicMax(&packed[(size_t)b * LL + m0 + wc * 64 + cg * 16 + lane], best);
    }
}

// ---------------- Kernel 4: decode packed -> S (d_out) + argmax (ws)
__global__ void decode_packed(const unsigned long long* __restrict__ packed,
                              float* __restrict__ S_out, int* __restrict__ arg) {
    int i = blockIdx.x * 256 + threadIdx.x;
    if (i < BB * LL) {
        unsigned long long p = packed[i];
        unsigned u = (unsigned)(p >> 32);
        unsigned bits = (u & 0x80000000u) ? (u & 0x7FFFFFFFu) : ~u;
        S_out[i] = __uint_as_float(bits);
        arg[i] = 4095 - (int)(unsigned)(p & 0xFFFFFFFFull);
    }
}

// ---------------- Kernel 5/7: batched 2D transpose src[R][Cc] -> dst[Cc][R]
__global__ __launch_bounds__(256) void transpose_mat(const float* __restrict__ src,
                                                     float* __restrict__ dst,
                                                     int R, int Cc) {
    __shared__ float tile[32][33];
    size_t boff = (size_t)blockIdx.z * R * Cc;
    int bx = blockIdx.x;
    int by = blockIdx.y;
    int tx = threadIdx.x & 31;
    int ty = threadIdx.x >> 5;
    const float* s = src + boff;
    float* d = dst + boff;
#pragma unroll
    for (int i = 0; i < 4; i++) {
        int r = by * 32 + ty + i * 8;
        int c = bx * 32 + tx;
        tile[ty + i * 8][tx] = s[(size_t)r * Cc + c];
    }
    __syncthreads();
#pragma unroll
    for (int i = 0; i < 4; i++) {
        int c = bx * 32 + ty + i * 8;
        int r = by * 32 + tx;
        d[(size_t)c * R + r] = tile[tx][ty + i * 8];
    }
}

// ---------------- Kernel 6: gather + fold (channel-last), one pixel per block
__global__ __launch_bounds__(256) void gather_fold(const float* __restrict__ value_t,
                                                   const int* __restrict__ arg,
                                                   float* __restrict__ T_t) {
    int b = blockIdx.y;
    int pix = blockIdx.x;
    int y = pix >> 6, x = pix & 63;
    int t = threadIdx.x;
    float2 acc = make_float2(0.f, 0.f);
    int cnty = (y == 0 || y == HH - 1) ? 2 : 3;
    int cntx = (x == 0 || x == WW - 1) ? 2 : 3;
    const int* ab = arg + b * LL;
    const float* vb = value_t + (size_t)b * LL * CC;
#pragma unroll
    for (int di = 0; di < 3; di++) {
        int my = y + 1 - di;
        if (my < 0 || my >= HH) continue;
#pragma unroll
        for (int dj = 0; dj < 3; dj++) {
            int mx = x + 1 - dj;
            if (mx < 0 || mx >= WW) continue;
            int a = ab[my * WW + mx];
            int ay = a >> 6, ax = a & 63;
            int vy = ay + di - 1, vx = ax + dj - 1;
            if (vy < 0 || vy >= HH || vx < 0 || vx >= WW) continue;
            float2 v = *(const float2*)&vb[((size_t)(vy * WW + vx)) * CC + t * 2];
            acc.x += v.x; acc.y += v.y;
        }
    }
    float inv = 1.0f / (float)(cnty * cntx);
    acc.x *= inv; acc.y *= inv;
    *(float2*)&T_t[((size_t)b * LL + pix) * CC + t * 2] = acc;
}

extern "C" void kernel_launch(void* const* d_in, const int* in_sizes, int n_in,
                              void* d_out, int out_size, void* d_ws, size_t ws_size,
                              hipStream_t stream) {
    const float* query = (const float*)d_in[0];
    const float* key   = (const float*)d_in[1];
    const float* value = (const float*)d_in[2];
    const float* Wemb  = (const float*)d_in[3];

    float* out   = (float*)d_out;
    float* S_out = out;
    float* T_out = out + BB * LL;

    char* ws = (char*)d_ws;
    // layout (55.2 MB total):
    char* img_ts = ws;                                   // 33,554,432 (dead after embed)
    char* Wst    = ws + 33554432;                        //  4,718,592 (dead after embed)
    char* qemb   = ws + 38273024;                        //  8,388,608 (dead after corr)
    char* kemb   = ws + 46661632;                        //  8,388,608 (dead after corr)
    unsigned long long* packed = (unsigned long long*)(ws + 55050240);  // 65,536
    char* zp     = ws + 55115776;                        //  4,096 (zeroed page)
    int*  arg    = (int*)(ws + 55119872);                // 32,768
    float* val_t = (float*)ws;                           // alias img_ts[0:16.78MB]
    float* T_t   = (float*)(ws + 16777216);              // alias img_ts[16.78:33.55MB]

    init_packed   <<<dim3(34), 256, 0, stream>>>(packed, 8704);  // packed + zp
    presplit      <<<dim3(64, 4), 256, 0, stream>>>(query, key, img_ts);
    splitW2b      <<<dim3(576), 256, 0, stream>>>(Wemb, Wst);
    embed_mfma    <<<dim3(64, 4), 512, 0, stream>>>(img_ts, Wst, zp, qemb, kemb);
    corr_max_mfma <<<dim3(32, 32, 2), 256, 0, stream>>>(kemb, qemb, packed);
    decode_packed <<<dim3(32), 256, 0, stream>>>(packed, S_out, arg);
    transpose_mat <<<dim3(128, 16, 2), 256, 0, stream>>>(value, val_t, CC, LL);
    gather_fold   <<<dim3(4096, 2), 256, 0, stream>>>(val_t, arg, T_t);
    transpose_mat <<<dim3(16, 128, 2), 256, 0, stream>>>(T_t, T_out, LL, CC);
}

// Round 10
// 221.688 us; speedup vs baseline: 1.1653x; 1.0343x over previous
//
#include <hip/hip_runtime.h>
#include <hip/hip_bf16.h>
#include <stdint.h>
#include <math.h>

#define BB 2
#define CC 512
#define HH 64
#define WW 64
#define LL 4096
#define DD 256
#define CIN 4608   // 512*9
#define NG 144     // gates = 16 c-chunks x 9 offsets

typedef _Float16 half_t;
typedef __attribute__((ext_vector_type(8))) _Float16 f16x8;
typedef __attribute__((ext_vector_type(4))) _Float16 f16x4;
typedef __attribute__((ext_vector_type(4))) float f32x4;

// ---------------- Kernel A: presplit images -> channel-last f16 hi/lo, swizzled
// img_ts layout: [img 4][y 64][cc 16][x 64][128B]; within 128B, phys 16B slot p
// holds logical slot (p ^ (x&7)).
__global__ __launch_bounds__(256) void presplit(const float* __restrict__ query,
                                                const float* __restrict__ key,
                                                char* __restrict__ img_ts) {
    __shared__ float tile[32][65];
    int img = blockIdx.y;               // b = img&1, type = img>>1
    int y   = blockIdx.x;
    const float* src = ((img >> 1) ? key : query) + (size_t)(img & 1) * CC * LL + y * WW;
    char* dstbase = img_ts + ((size_t)img * 64 + y) * (16 * 64 * 128);
    int t = threadIdx.x;
    int xl = t & 63, c4 = t >> 6;
    int xw = t >> 2, fsw = t & 3;
    for (int cc = 0; cc < 16; ++cc) {
#pragma unroll
        for (int j = 0; j < 8; ++j) {
            int cl = c4 + j * 4;
            tile[cl][xl] = src[(size_t)(cc * 32 + cl) * LL + xl];
        }
        __syncthreads();
        f16x8 h8, l8;
#pragma unroll
        for (int j = 0; j < 8; ++j) {
            float v = tile[fsw * 8 + j][xw];
            half_t h = (half_t)v;
            h8[j] = h; l8[j] = (half_t)(v - (float)h);
        }
        char* p = dstbase + (size_t)cc * 8192 + xw * 128;
        int swz = (xw & 7) << 4;
        *(f16x8*)(p + ((fsw * 16) ^ swz)) = h8;
        *(f16x8*)(p + ((64 + fsw * 16) ^ swz)) = l8;
        __syncthreads();
    }
}

// ---------------- Kernel B: repack W into per-gate tiles [g = cc*9+o][d][128B]
__global__ __launch_bounds__(256) void splitW2b(const float* __restrict__ W,
                                                char* __restrict__ Wst) {
    int i = blockIdx.x * 256 + threadIdx.x;   // NG*DD*4 = 147456
    if (i >= NG * DD * 4) return;
    int g  = i >> 10;
    int r  = i & 1023;
    int d  = r >> 2;
    int fs = r & 3;
    int cc = g / 9, o = g - cc * 9;
    const float* src = W + (size_t)d * CIN;
    f16x8 h8, l8;
#pragma unroll
    for (int j = 0; j < 8; j++) {
        float w = src[(cc * 32 + fs * 8 + j) * 9 + o];
        half_t h = (half_t)w;
        h8[j] = h;
        l8[j] = (half_t)(w - (float)h);
    }
    size_t base = (size_t)g * 32768 + d * 128;
    int sw = (d & 7) << 4;
    *(f16x8*)(Wst + base + ((fs * 16) ^ sw)) = h8;
    *(f16x8*)(Wst + base + ((64 + fs * 16) ^ sw)) = l8;
}

#define GATE() do { asm volatile("s_waitcnt vmcnt(0) lgkmcnt(0)" ::: "memory"); \
                    __builtin_amdgcn_s_barrier(); \
                    __builtin_amdgcn_sched_barrier(0); } while (0)

// ---------------- Kernel 1: embed, offset-decomposed, K-split x2.
// Block: 256d x 128l (2 image rows), 8 waves (4d x 2l), wave = 64d x 64l.
// 72 gates (8 c-chunks x 9 offsets) per block; partial f32 [d][l] output.
__global__ __launch_bounds__(512, 1) void embed_mfma(const char* __restrict__ img_ts,
                                                     const char* __restrict__ Wst,
                                                     const char* __restrict__ zp,
                                                     float* __restrict__ part) {
    __shared__ char sW[2][32768];       // W gate tiles (swizzled)
    __shared__ char sB[2][33792];       // B tiles: [ri 4][xi 66][128B]

    int iid = blockIdx.y;               // image 0..3
    int ks  = blockIdx.z;               // K half 0..1
    int lt  = blockIdx.x;               // l-tile 0..31
    int y0  = lt * 2;                   // first image row of tile
    int t = threadIdx.x;
    int w = t >> 6, lane = t & 63;
    int wr = w >> 1, wc = w & 1;        // wave: d base wr*64, output row y0+wc
    int fr = lane & 15, fs = lane >> 4;

    // B-DMA sources (5 calls; 5th only wave 0). img_ts phys-swizzled -> linear copy.
    const char* imgb = img_ts + (size_t)iid * (64 * 16 * 64 * 128) + (size_t)ks * 65536;
    const char *ps0, *ps1, *ps2, *ps3, *ps4;
    int pb0, pb1, pb2, pb3, pb4;
#define PREP(qv, PS, PB)                                                \
    {                                                                   \
        int q = (qv);                                                   \
        int ri = q / 528;                                               \
        int rem = q - ri * 528;                                         \
        int xi = rem >> 3, sub = rem & 7;                               \
        int xg = xi - 1, yg = y0 - 1 + ri;                              \
        bool ok = (yg >= 0) && (yg < 64) && (xg >= 0) && (xg < 64);     \
        PS = ok ? imgb + (size_t)yg * 131072 + (size_t)xg * 128 + sub * 16 \
                : zp + ((q & 255) * 16);                                \
        PB = ok ? 8192 : 0;                                             \
    }
    PREP(t, ps0, pb0); PREP(512 + t, ps1, pb1); PREP(1024 + t, ps2, pb2);
    PREP(1536 + t, ps3, pb3); PREP(2048 + t, ps4, pb4);

    const char* pW = Wst + (size_t)ks * 72 * 32768;

#define GLL(src, dst)                                                   \
    __builtin_amdgcn_global_load_lds(                                   \
        (const __attribute__((address_space(1))) void*)(src),           \
        (__attribute__((address_space(3))) void*)(dst), 16, 0, 0)

#define DMAW(dst)                                                       \
    do {                                                                \
        _Pragma("unroll")                                               \
        for (int c = 0; c < 4; c++)                                     \
            GLL(pW + c * 8192 + t * 16, (dst) + c * 8192 + t * 16);     \
        pW += 32768;                                                    \
    } while (0)

#define DMAB(dst)                                                       \
    do {                                                                \
        GLL(ps0, (dst) + t * 16);                                       \
        GLL(ps1, (dst) + 8192 + t * 16);                                \
        GLL(ps2, (dst) + 16384 + t * 16);                               \
        GLL(ps3, (dst) + 24576 + t * 16);                               \
        if (t < 64) GLL(ps4, (dst) + 32768 + t * 16);                   \
        ps0 += pb0; ps1 += pb1; ps2 += pb2; ps3 += pb3; ps4 += pb4;     \
    } while (0)

#define READA(wbuf)                                                     \
    do {                                                                \
        _Pragma("unroll")                                               \
        for (int rg = 0; rg < 4; rg++) {                                \
            int dl = wr * 64 + rg * 16 + fr;                            \
            int sw_ = (dl & 7) << 4;                                    \
            const char* rowp = (const char*)(wbuf) + dl * 128;          \
            ah[rg] = *(const f16x8*)(rowp + ((fs * 16) ^ sw_));         \
            al[rg] = *(const f16x8*)(rowp + ((64 + fs * 16) ^ sw_));    \
        }                                                               \
    } while (0)

#define READB(bbuf, di_, dj_)                                           \
    do {                                                                \
        int ri = wc + (di_);                                            \
        _Pragma("unroll")                                               \
        for (int cg = 0; cg < 4; cg++) {                                \
            int xi = cg * 16 + fr + (dj_);                              \
            int sw_ = ((xi - 1) & 7) << 4;                              \
            const char* rowp = (const char*)(bbuf) + ri * 8448 + xi * 128; \
            bh[cg] = *(const f16x8*)(rowp + ((fs * 16) ^ sw_));         \
            bl[cg] = *(const f16x8*)(rowp + ((64 + fs * 16) ^ sw_));    \
        }                                                               \
    } while (0)

#define DOMFMA()                                                        \
    do {                                                                \
        _Pragma("unroll")                                               \
        for (int rg = 0; rg < 4; rg++)                                  \
            _Pragma("unroll")                                           \
            for (int cg = 0; cg < 4; cg++)                              \
                acc[rg][cg] = __builtin_amdgcn_mfma_f32_16x16x32_f16(ah[rg], bh[cg], acc[rg][cg], 0, 0, 0); \
        _Pragma("unroll")                                               \
        for (int rg = 0; rg < 4; rg++)                                  \
            _Pragma("unroll")                                           \
            for (int cg = 0; cg < 4; cg++) {                            \
                acc[rg][cg] = __builtin_amdgcn_mfma_f32_16x16x32_f16(ah[rg], bl[cg], acc[rg][cg], 0, 0, 0); \
                acc[rg][cg] = __builtin_amdgcn_mfma_f32_16x16x32_f16(al[rg], bh[cg], acc[rg][cg], 0, 0, 0); \
            }                                                           \
    } while (0)

    f32x4 acc[4][4];
#pragma unroll
    for (int rg = 0; rg < 4; rg++)
#pragma unroll
        for (int cg = 0; cg < 4; cg++) acc[rg][cg] = (f32x4){0.f, 0.f, 0.f, 0.f};

    f16x8 ah[4], al[4], bh[4], bl[4];

    char* wb0 = &sW[0][0]; char* wb1 = &sW[1][0];
    char* b0 = &sB[0][0];  char* b1 = &sB[1][0];

    // ---- prologue: B chunk 0 + W gate 0
    DMAB(b0);
    DMAW(wb0);
    GATE();

    char* wcur = wb0; char* wnext = wb1;
    char* bcur = b0;  char* bnext = b1;
    int o = 0, ccl = 0;

#pragma unroll 1
    for (int g = 0; g < 72; ++g) {
        int di_ = (o >= 6) ? 2 : (o >= 3) ? 1 : 0;
        int dj_ = o - di_ * 3;
        READA(wcur);
        READB(bcur, di_, dj_);
        if (g < 71) DMAW(wnext);
        if (o == 8 && ccl < 7) DMAB(bnext);
        __builtin_amdgcn_sched_barrier(0);
        DOMFMA();
        GATE();
        { char* tp = wcur; wcur = wnext; wnext = tp; }
        if (o == 8) { char* tp = bcur; bcur = bnext; bnext = tp; o = 0; ccl++; }
        else o++;
    }

    // ---- epilogue: store f32 partial [256d][128l]
    float* pt = part + (((size_t)iid * 32 + lt) * 2 + ks) * 32768;
#pragma unroll
    for (int rg = 0; rg < 4; rg++)
#pragma unroll
        for (int cg = 0; cg < 4; cg++) {
            int l = wc * 64 + cg * 16 + fr;
            int d0 = wr * 64 + rg * 16 + fs * 4;
#pragma unroll
            for (int r = 0; r < 4; r++)
                pt[(d0 + r) * 128 + l] = acc[rg][cg][r];
        }
#undef PREP
#undef GLL
#undef DMAW
#undef DMAB
#undef READA
#undef READB
#undef DOMFMA
}

// ---------------- Kernel 1b: sum K-halves + D-norm + emit swizzled f16 hi/lo rows
// grid (64, 4): block handles [256d][64l] of one image's partial tile.
__global__ __launch_bounds__(256) void norm_split(const float* __restrict__ part,
                                                  char* __restrict__ qemb,
                                                  char* __restrict__ kemb) {
    __shared__ float sm[4][64];
    __shared__ float invn[64];
    __shared__ char stage[64][1040];    // 16B-aligned stride, bank-offset 4/row

    int iid = blockIdx.y;
    int bx  = blockIdx.x;               // 0..63
    int lt  = bx >> 1, lh2 = bx & 1;
    const float* p0 = part + (((size_t)iid * 32 + lt) * 2 + 0) * 32768 + lh2 * 64;
    const float* p1 = p0 + 32768;
    int t = threadIdx.x;
    int ll = t & 63, dq = t >> 6;       // l-local 0..63, d-quarter 0..3

    // phase 1: sum of squares over d
    float sq = 0.f;
    for (int dd = 0; dd < 64; ++dd) {
        int d = dq * 64 + dd;
        float v = p0[d * 128 + ll] + p1[d * 128 + ll];
        sq += v * v;
    }
    sm[dq][ll] = sq;
    __syncthreads();
    if (t < 64) {
        float s = sm[0][t] + sm[1][t] + sm[2][t] + sm[3][t];
        invn[t] = 1.0f / fmaxf(sqrtf(s), 1e-12f);
    }
    __syncthreads();

    // phase 2: scale + split to f16 hi/lo, build swizzled row bytes in LDS
    float sc = invn[ll];
    int swb = (ll & 7) << 4;            // (l&7) == (ll&7): l = lt*128 + lh2*64 + ll
    for (int oc = 0; oc < 8; ++oc) {
        int d0 = dq * 64 + oc * 8;
        f16x8 h8, l8;
#pragma unroll
        for (int j = 0; j < 8; ++j) {
            int d = d0 + j;
            float v = (p0[d * 128 + ll] + p1[d * 128 + ll]) * sc;
            half_t h = (half_t)v;
            h8[j] = h;
            l8[j] = (half_t)(v - (float)h);
        }
        int itb = d0 >> 5;
        int fsc = (d0 >> 3) & 3;
        *(f16x8*)&stage[ll][itb * 128 + ((fsc * 16) ^ swb)] = h8;
        *(f16x8*)&stage[ll][itb * 128 + ((64 + fsc * 16) ^ swb)] = l8;
    }
    __syncthreads();

    // dump 64 rows x 1024B to emb
    int b = iid & 1, type = iid >> 1;
    char* e = (type ? kemb : qemb);
    int rr = t >> 2, c0 = t & 3;
    char* erow = e + ((size_t)b * LL + lt * 128 + lh2 * 64 + rr) * 1024;
    const char* srow = &stage[rr][0];
#pragma unroll
    for (int c = 0; c < 16; ++c) {
        int cj = c0 + c * 4;
        *(float4*)(erow + cj * 16) = *(const float4*)(srow + cj * 16);
    }
}

// ---------------- Kernel 2: zero init (packed max buffer + zero page)
__global__ void init_packed(unsigned long long* p, int n) {
    int i = blockIdx.x * 256 + threadIdx.x;
    if (i < n) p[i] = 0ull;
}

// ---------------- Kernel 3: corr via LDS-staged split-3 MFMA + fused max/argmax
__global__ __launch_bounds__(256, 2) void corr_max_mfma(const char* __restrict__ kemb,
                                                        const char* __restrict__ qemb,
                                                        unsigned long long* __restrict__ packed) {
    __shared__ char sA[2][16384];
    __shared__ char sBq[2][16384];

    int b  = blockIdx.z;
    int l0 = blockIdx.y * 128;
    int m0 = blockIdx.x * 128;
    int t  = threadIdx.x;
    int w = t >> 6, lane = t & 63;
    int wr = w >> 1, wc = w & 1;
    int fr = lane & 15, fs = lane >> 4;

    const char* Abase = kemb + ((size_t)b * LL + l0) * 1024;
    const char* Bbase = qemb + ((size_t)b * LL + m0) * 1024;

    f32x4 acc[4][4];
#pragma unroll
    for (int i = 0; i < 4; i++)
#pragma unroll
        for (int j = 0; j < 4; j++) acc[i][j] = (f32x4){0.f, 0.f, 0.f, 0.f};

#define DMA2(bufi, itv)                                                   \
    do {                                                                  \
        _Pragma("unroll")                                                 \
        for (int c = 0; c < 4; c++) {                                     \
            int idx = c * 4096 + t * 16;                                  \
            int row = idx >> 7, offb = idx & 127;                         \
            __builtin_amdgcn_global_load_lds(                             \
                (const __attribute__((address_space(1))) void*)(Abase + (size_t)row * 1024 + (itv) * 128 + offb), \
                (__attribute__((address_space(3))) void*)(&sA[bufi][idx]), 16, 0, 0); \
        }                                                                 \
        _Pragma("unroll")                                                 \
        for (int c = 0; c < 4; c++) {                                     \
            int idx = c * 4096 + t * 16;                                  \
            int row = idx >> 7, offb = idx & 127;                         \
            __builtin_amdgcn_global_load_lds(                             \
                (const __attribute__((address_space(1))) void*)(Bbase + (size_t)row * 1024 + (itv) * 128 + offb), \
                (__attribute__((address_space(3))) void*)(&sBq[bufi][idx]), 16, 0, 0); \
        }                                                                 \
    } while (0)

    DMA2(0, 0);

    f16x8 ah[4], al[4], bh[4], bl[4];
    for (int it = 0; it < 8; ++it) {
        asm volatile("s_waitcnt vmcnt(0) lgkmcnt(0)" ::: "memory");
        __builtin_amdgcn_s_barrier();
        __builtin_amdgcn_sched_barrier(0);
        if (it < 7) DMA2((it + 1) & 1, it + 1);
        __builtin_amdgcn_sched_barrier(0);
        const char* sa = sA[it & 1];
        const char* sb = sBq[it & 1];
#pragma unroll
        for (int rg = 0; rg < 4; rg++) {
            int r = wr * 64 + rg * 16 + fr;
            const char* rp = sa + r * 128;
            int sw_ = (r & 7) << 4;
            ah[rg] = *(const f16x8*)(rp + ((fs * 16) ^ sw_));
            al[rg] = *(const f16x8*)(rp + ((64 + fs * 16) ^ sw_));
        }
#pragma unroll
        for (int cg = 0; cg < 4; cg++) {
            int r = wc * 64 + cg * 16 + fr;
            const char* rp = sb + r * 128;
            int sw_ = (r & 7) << 4;
            bh[cg] = *(const f16x8*)(rp + ((fs * 16) ^ sw_));
            bl[cg] = *(const f16x8*)(rp + ((64 + fs * 16) ^ sw_));
        }
#pragma unroll
        for (int rg = 0; rg < 4; rg++)
#pragma unroll
            for (int cg = 0; cg < 4; cg++)
                acc[rg][cg] = __builtin_amdgcn_mfma_f32_16x16x32_f16(ah[rg], bh[cg], acc[rg][cg], 0, 0, 0);
#pragma unroll
        for (int rg = 0; rg < 4; rg++)
#pragma unroll
            for (int cg = 0; cg < 4; cg++) {
                acc[rg][cg] = __builtin_amdgcn_mfma_f32_16x16x32_f16(ah[rg], bl[cg], acc[rg][cg], 0, 0, 0);
                acc[rg][cg] = __builtin_amdgcn_mfma_f32_16x16x32_f16(al[rg], bh[cg], acc[rg][cg], 0, 0, 0);
            }
    }
#undef DMA2

#pragma unroll
    for (int cg = 0; cg < 4; cg++) {
        unsigned long long best = 0ull;
#pragma unroll
        for (int rg = 0; rg < 4; rg++) {
#pragma unroll
            for (int r = 0; r < 4; r++) {
                unsigned u = __float_as_uint(acc[rg][cg][r]);
                u = (u & 0x80000000u) ? ~u : (u | 0x80000000u);
                int l = l0 + wr * 64 + rg * 16 + fs * 4 + r;
                unsigned long long p = ((unsigned long long)u << 32) | (unsigned)(4095 - l);
                best = (p > best) ? p : best;
            }
        }
        unsigned long long oo;
        oo = __shfl_xor(best, 16); best = (oo > best) ? oo : best;
        oo = __shfl_xor(best, 32); best = (oo > best) ? oo : best;
        if (lane < 16)
            atomicMax(&packed[(size_t)b * LL + m0 + wc * 64 + cg * 16 + lane], best);
    }
}

// ---------------- Kernel 4: decode packed -> S (d_out) + argmax (ws)
__global__ void decode_packed(const unsigned long long* __restrict__ packed,
                              float* __restrict__ S_out, int* __restrict__ arg) {
    int i = blockIdx.x * 256 + threadIdx.x;
    if (i < BB * LL) {
        unsigned long long p = packed[i];
        unsigned u = (unsigned)(p >> 32);
        unsigned bits = (u & 0x80000000u) ? (u & 0x7FFFFFFFu) : ~u;
        S_out[i] = __uint_as_float(bits);
        arg[i] = 4095 - (int)(unsigned)(p & 0xFFFFFFFFull);
    }
}

// ---------------- Kernel 5/7: batched 2D transpose src[R][Cc] -> dst[Cc][R]
__global__ __launch_bounds__(256) void transpose_mat(const float* __restrict__ src,
                                                     float* __restrict__ dst,
                                                     int R, int Cc) {
    __shared__ float tile[32][33];
    size_t boff = (size_t)blockIdx.z * R * Cc;
    int bx = blockIdx.x;
    int by = blockIdx.y;
    int tx = threadIdx.x & 31;
    int ty = threadIdx.x >> 5;
    const float* s = src + boff;
    float* d = dst + boff;
#pragma unroll
    for (int i = 0; i < 4; i++) {
        int r = by * 32 + ty + i * 8;
        int c = bx * 32 + tx;
        tile[ty + i * 8][tx] = s[(size_t)r * Cc + c];
    }
    __syncthreads();
#pragma unroll
    for (int i = 0; i < 4; i++) {
        int c = bx * 32 + ty + i * 8;
        int r = by * 32 + tx;
        d[(size_t)c * R + r] = tile[tx][ty + i * 8];
    }
}

// ---------------- Kernel 6: gather + fold (channel-last), one pixel per block
__global__ __launch_bounds__(256) void gather_fold(const float* __restrict__ value_t,
                                                   const int* __restrict__ arg,
                                                   float* __restrict__ T_t) {
    int b = blockIdx.y;
    int pix = blockIdx.x;
    int y = pix >> 6, x = pix & 63;
    int t = threadIdx.x;
    float2 acc = make_float2(0.f, 0.f);
    int cnty = (y == 0 || y == HH - 1) ? 2 : 3;
    int cntx = (x == 0 || x == WW - 1) ? 2 : 3;
    const int* ab = arg + b * LL;
    const float* vb = value_t + (size_t)b * LL * CC;
#pragma unroll
    for (int di = 0; di < 3; di++) {
        int my = y + 1 - di;
        if (my < 0 || my >= HH) continue;
#pragma unroll
        for (int dj = 0; dj < 3; dj++) {
            int mx = x + 1 - dj;
            if (mx < 0 || mx >= WW) continue;
            int a = ab[my * WW + mx];
            int ay = a >> 6, ax = a & 63;
            int vy = ay + di - 1, vx = ax + dj - 1;
            if (vy < 0 || vy >= HH || vx < 0 || vx >= WW) continue;
            float2 v = *(const float2*)&vb[((size_t)(vy * WW + vx)) * CC + t * 2];
            acc.x += v.x; acc.y += v.y;
        }
    }
    float inv = 1.0f / (float)(cnty * cntx);
    acc.x *= inv; acc.y *= inv;
    *(float2*)&T_t[((size_t)b * LL + pix) * CC + t * 2] = acc;
}

extern "C" void kernel_launch(void* const* d_in, const int* in_sizes, int n_in,
                              void* d_out, int out_size, void* d_ws, size_t ws_size,
                              hipStream_t stream) {
    const float* query = (const float*)d_in[0];
    const float* key   = (const float*)d_in[1];
    const float* value = (const float*)d_in[2];
    const float* Wemb  = (const float*)d_in[3];

    float* out   = (float*)d_out;
    float* S_out = out;
    float* T_out = out + BB * LL;

    char* ws = (char*)d_ws;
    // layout (~88.7 MB):
    char*  img_ts = ws;                                  // 33,554,432 (dead after embed)
    char*  Wst    = ws + 33554432;                       //  4,718,592 (dead after embed)
    float* part   = (float*)(ws + 38273024);             // 33,554,432 (dead after norm_split)
    char*  qemb   = ws + 71827456;                       //  8,388,608 (dead after corr)
    char*  kemb   = ws + 80216064;                       //  8,388,608 (dead after corr)
    unsigned long long* packed = (unsigned long long*)(ws + 88604672);  // 65,536
    char*  zp     = ws + 88670208;                       //  4,096 (zeroed page)
    int*   arg    = (int*)(ws + 88674304);               // 32,768
    float* val_t  = (float*)(ws + 38273024);             // alias part[0:16.78MB]
    float* T_t    = (float*)(ws + 38273024 + 16777216);  // alias part[16.78:33.55MB]

    init_packed   <<<dim3(34), 256, 0, stream>>>(packed, 8704);  // packed + zp
    presplit      <<<dim3(64, 4), 256, 0, stream>>>(query, key, img_ts);
    splitW2b      <<<dim3(576), 256, 0, stream>>>(Wemb, Wst);
    embed_mfma    <<<dim3(32, 4, 2), 512, 0, stream>>>(img_ts, Wst, zp, part);
    norm_split    <<<dim3(64, 4), 256, 0, stream>>>(part, qemb, kemb);
    corr_max_mfma <<<dim3(32, 32, 2), 256, 0, stream>>>(kemb, qemb, packed);
    decode_packed <<<dim3(32), 256, 0, stream>>>(packed, S_out, arg);
    transpose_mat <<<dim3(128, 16, 2), 256, 0, stream>>>(value, val_t, CC, LL);
    gather_fold   <<<dim3(4096, 2), 256, 0, stream>>>(val_t, arg, T_t);
    transpose_mat <<<dim3(16, 128, 2), 256, 0, stream>>>(T_t, T_out, LL, CC);
}

// Round 11
// 219.045 us; speedup vs baseline: 1.1793x; 1.0121x over previous
//
#include <hip/hip_runtime.h>
#include <hip/hip_bf16.h>
#include <stdint.h>
#include <math.h>

#define BB 2
#define CC 512
#define HH 64
#define WW 64
#define LL 4096
#define DD 256
#define CIN 4608   // 512*9
#define NG 144     // gates = 16 c-chunks x 9 offsets

typedef _Float16 half_t;
typedef __attribute__((ext_vector_type(8))) _Float16 f16x8;
typedef __attribute__((ext_vector_type(4))) _Float16 f16x4;
typedef __attribute__((ext_vector_type(4))) float f32x4;

// ---------------- Kernel A: presplit images -> channel-last f16 hi/lo, swizzled
// img_ts layout: [img 4][y 64][cc 16][x 64][128B]; within 128B, phys 16B slot p
// holds logical slot (p ^ (x&7)).
__global__ __launch_bounds__(256) void presplit(const float* __restrict__ query,
                                                const float* __restrict__ key,
                                                char* __restrict__ img_ts) {
    __shared__ float tile[32][65];
    int img = blockIdx.y;               // b = img&1, type = img>>1
    int y   = blockIdx.x;
    const float* src = ((img >> 1) ? key : query) + (size_t)(img & 1) * CC * LL + y * WW;
    char* dstbase = img_ts + ((size_t)img * 64 + y) * (16 * 64 * 128);
    int t = threadIdx.x;
    int xl = t & 63, c4 = t >> 6;
    int xw = t >> 2, fsw = t & 3;
    for (int cc = 0; cc < 16; ++cc) {
#pragma unroll
        for (int j = 0; j < 8; ++j) {
            int cl = c4 + j * 4;
            tile[cl][xl] = src[(size_t)(cc * 32 + cl) * LL + xl];
        }
        __syncthreads();
        f16x8 h8, l8;
#pragma unroll
        for (int j = 0; j < 8; ++j) {
            float v = tile[fsw * 8 + j][xw];
            half_t h = (half_t)v;
            h8[j] = h; l8[j] = (half_t)(v - (float)h);
        }
        char* p = dstbase + (size_t)cc * 8192 + xw * 128;
        int swz = (xw & 7) << 4;
        *(f16x8*)(p + ((fsw * 16) ^ swz)) = h8;
        *(f16x8*)(p + ((64 + fsw * 16) ^ swz)) = l8;
        __syncthreads();
    }
}

// ---------------- Kernel B: repack W into per-gate tiles [g = cc*9+o][d][128B]
__global__ __launch_bounds__(256) void splitW2b(const float* __restrict__ W,
                                                char* __restrict__ Wst) {
    int i = blockIdx.x * 256 + threadIdx.x;   // NG*DD*4 = 147456
    if (i >= NG * DD * 4) return;
    int g  = i >> 10;
    int r  = i & 1023;
    int d  = r >> 2;
    int fs = r & 3;
    int cc = g / 9, o = g - cc * 9;
    const float* src = W + (size_t)d * CIN;
    f16x8 h8, l8;
#pragma unroll
    for (int j = 0; j < 8; j++) {
        float w = src[(cc * 32 + fs * 8 + j) * 9 + o];
        half_t h = (half_t)w;
        h8[j] = h;
        l8[j] = (half_t)(w - (float)h);
    }
    size_t base = (size_t)g * 32768 + d * 128;
    int sw = (d & 7) << 4;
    *(f16x8*)(Wst + base + ((fs * 16) ^ sw)) = h8;
    *(f16x8*)(Wst + base + ((64 + fs * 16) ^ sw)) = l8;
}

#define GATE() do { asm volatile("s_waitcnt vmcnt(0) lgkmcnt(0)" ::: "memory"); \
                    __builtin_amdgcn_s_barrier(); \
                    __builtin_amdgcn_sched_barrier(0); } while (0)

// ---------------- Kernel 1: embed, offset-decomposed, K-split x2.
// Block: 256d x 128l (2 image rows), 8 waves (4d x 2l), wave = 64d x 64l.
// 72 gates; ONE-GATE-AHEAD register pipeline: gate g reads fragments for g+1
// (W(g+1)/B resident), DMAs W(g+2) into the buffer W(g) vacated, then MFMAs
// gate g from registers with zero LDS dependency. GATE's lgkm(0) fences
// this gate's reads against next gate's DMA overwrite.
__global__ __launch_bounds__(512, 2) void embed_mfma(const char* __restrict__ img_ts,
                                                     const char* __restrict__ Wst,
                                                     const char* __restrict__ zp,
                                                     float* __restrict__ part) {
    __shared__ char sW[2][32768];       // W gate tiles (swizzled)
    __shared__ char sB[2][33792];       // B tiles: [ri 4][xi 66][128B]

    int iid = blockIdx.y;               // image 0..3
    int ks  = blockIdx.z;               // K half 0..1
    int lt  = blockIdx.x;               // l-tile 0..31
    int y0  = lt * 2;                   // first image row of tile
    int t = threadIdx.x;
    int w = t >> 6, lane = t & 63;
    int wr = w >> 1, wc = w & 1;        // wave: d base wr*64, output row y0+wc
    int fr = lane & 15, fs = lane >> 4;

    // B-DMA sources (5 calls; 5th only wave 0). img_ts phys-swizzled -> linear copy.
    const char* imgb = img_ts + (size_t)iid * (64 * 16 * 64 * 128) + (size_t)ks * 65536;
    const char *ps0, *ps1, *ps2, *ps3, *ps4;
    int pb0, pb1, pb2, pb3, pb4;
#define PREP(qv, PS, PB)                                                \
    {                                                                   \
        int q = (qv);                                                   \
        int ri = q / 528;                                               \
        int rem = q - ri * 528;                                         \
        int xi = rem >> 3, sub = rem & 7;                               \
        int xg = xi - 1, yg = y0 - 1 + ri;                              \
        bool ok = (yg >= 0) && (yg < 64) && (xg >= 0) && (xg < 64);     \
        PS = ok ? imgb + (size_t)yg * 131072 + (size_t)xg * 128 + sub * 16 \
                : zp + ((q & 255) * 16);                                \
        PB = ok ? 8192 : 0;                                             \
    }
    PREP(t, ps0, pb0); PREP(512 + t, ps1, pb1); PREP(1024 + t, ps2, pb2);
    PREP(1536 + t, ps3, pb3); PREP(2048 + t, ps4, pb4);

    const char* pW = Wst + (size_t)ks * 72 * 32768;

#define GLL(src, dst)                                                   \
    __builtin_amdgcn_global_load_lds(                                   \
        (const __attribute__((address_space(1))) void*)(src),           \
        (__attribute__((address_space(3))) void*)(dst), 16, 0, 0)

#define DMAW(dst)                                                       \
    do {                                                                \
        _Pragma("unroll")                                               \
        for (int c = 0; c < 4; c++)                                     \
            GLL(pW + c * 8192 + t * 16, (dst) + c * 8192 + t * 16);     \
        pW += 32768;                                                    \
    } while (0)

#define DMAB(dst)                                                       \
    do {                                                                \
        GLL(ps0, (dst) + t * 16);                                       \
        GLL(ps1, (dst) + 8192 + t * 16);                                \
        GLL(ps2, (dst) + 16384 + t * 16);                               \
        GLL(ps3, (dst) + 24576 + t * 16);                               \
        if (t < 64) GLL(ps4, (dst) + 32768 + t * 16);                   \
        ps0 += pb0; ps1 += pb1; ps2 += pb2; ps3 += pb3; ps4 += pb4;     \
    } while (0)

#define READA(AH, AL, wbuf)                                             \
    do {                                                                \
        _Pragma("unroll")                                               \
        for (int rg = 0; rg < 4; rg++) {                                \
            int dl = wr * 64 + rg * 16 + fr;                            \
            int sw_ = (dl & 7) << 4;                                    \
            const char* rowp = (const char*)(wbuf) + dl * 128;          \
            AH[rg] = *(const f16x8*)(rowp + ((fs * 16) ^ sw_));         \
            AL[rg] = *(const f16x8*)(rowp + ((64 + fs * 16) ^ sw_));    \
        }                                                               \
    } while (0)

#define READB(BH, BL, bbuf, di_, dj_)                                   \
    do {                                                                \
        int ri = wc + (di_);                                            \
        _Pragma("unroll")                                               \
        for (int cg = 0; cg < 4; cg++) {                                \
            int xi = cg * 16 + fr + (dj_);                              \
            int sw_ = ((xi - 1) & 7) << 4;                              \
            const char* rowp = (const char*)(bbuf) + ri * 8448 + xi * 128; \
            BH[cg] = *(const f16x8*)(rowp + ((fs * 16) ^ sw_));         \
            BL[cg] = *(const f16x8*)(rowp + ((64 + fs * 16) ^ sw_));    \
        }                                                               \
    } while (0)

#define DOMFMA(AH, AL, BH, BL)                                          \
    do {                                                                \
        _Pragma("unroll")                                               \
        for (int rg = 0; rg < 4; rg++)                                  \
            _Pragma("unroll")                                           \
            for (int cg = 0; cg < 4; cg++)                              \
                acc[rg][cg] = __builtin_amdgcn_mfma_f32_16x16x32_f16(AH[rg], BH[cg], acc[rg][cg], 0, 0, 0); \
        _Pragma("unroll")                                               \
        for (int rg = 0; rg < 4; rg++)                                  \
            _Pragma("unroll")                                           \
            for (int cg = 0; cg < 4; cg++) {                            \
                acc[rg][cg] = __builtin_amdgcn_mfma_f32_16x16x32_f16(AH[rg], BL[cg], acc[rg][cg], 0, 0, 0); \
                acc[rg][cg] = __builtin_amdgcn_mfma_f32_16x16x32_f16(AL[rg], BH[cg], acc[rg][cg], 0, 0, 0); \
            }                                                           \
    } while (0)

    f32x4 acc[4][4];
#pragma unroll
    for (int rg = 0; rg < 4; rg++)
#pragma unroll
        for (int cg = 0; cg < 4; cg++) acc[rg][cg] = (f32x4){0.f, 0.f, 0.f, 0.f};

    f16x8 ah0[4], al0[4], bh0[4], bl0[4];
    f16x8 ah1[4], al1[4], bh1[4], bl1[4];

    char* wb0 = &sW[0][0]; char* wb1 = &sW[1][0];
    char* b0 = &sB[0][0];  char* b1 = &sB[1][0];

    // ---- prologue: W(0),B(0) resident; read frags(0); issue W(1); fence.
    DMAB(b0);
    DMAW(wb0);
    GATE();
    READA(ah0, al0, wb0);
    READB(bh0, bl0, b0, 0, 0);          // gate 0: o=0 (di=0,dj=0)
    DMAW(wb1);                          // W(1)
    GATE();                             // fences W(1) + frags(0) reads

#pragma unroll 1
    for (int g = 0; g < 72; g += 2) {
        // ---- even gate g: read set1 for g+1; DMA W(g+2) into wb0; MFMA set0
        {
            int g1 = g + 1;             // always < 72
            int c1 = g1 / 9, o1 = g1 - c1 * 9;
            int di_ = (o1 >= 6) ? 2 : (o1 >= 3) ? 1 : 0;
            int dj_ = o1 - di_ * 3;
            READA(ah1, al1, wb1);                       // W(g+1) in wb[(g+1)&1]=wb1
            READB(bh1, bl1, (c1 & 1) ? b1 : b0, di_, dj_);
        }
        if (g + 2 < 72) DMAW(wb0);                      // W(g+2): wb0 vacated (read at g-1)
        {
            int cg_ = g / 9;
            int c2 = cg_ + 1;
            if (g - cg_ * 9 == 7 && c2 < 8) DMAB((c2 & 1) ? b1 : b0);
        }
        __builtin_amdgcn_sched_barrier(0);
        DOMFMA(ah0, al0, bh0, bl0);
        GATE();
        // ---- odd gate g+1: read set0 for g+2; DMA W(g+3) into wb1; MFMA set1
        if (g + 2 < 72) {
            int g2 = g + 2;
            int c1 = g2 / 9, o1 = g2 - c1 * 9;
            int di_ = (o1 >= 6) ? 2 : (o1 >= 3) ? 1 : 0;
            int dj_ = o1 - di_ * 3;
            READA(ah0, al0, wb0);                       // W(g+2) in wb0 (fenced above)
            READB(bh0, bl0, (c1 & 1) ? b1 : b0, di_, dj_);
            if (g + 3 < 72) DMAW(wb1);                  // W(g+3): wb1 vacated this gate
            int g1v = g + 1;
            int cg_ = g1v / 9;
            int c2 = cg_ + 1;
            if (g1v - cg_ * 9 == 7 && c2 < 8) DMAB((c2 & 1) ? b1 : b0);
        }
        __builtin_amdgcn_sched_barrier(0);
        DOMFMA(ah1, al1, bh1, bl1);
        GATE();
    }

    // ---- epilogue: store f32 partial [256d][128l]
    float* pt = part + (((size_t)iid * 32 + lt) * 2 + ks) * 32768;
#pragma unroll
    for (int rg = 0; rg < 4; rg++)
#pragma unroll
        for (int cg = 0; cg < 4; cg++) {
            int l = wc * 64 + cg * 16 + fr;
            int d0 = wr * 64 + rg * 16 + fs * 4;
#pragma unroll
            for (int r = 0; r < 4; r++)
                pt[(d0 + r) * 128 + l] = acc[rg][cg][r];
        }
#undef PREP
#undef GLL
#undef DMAW
#undef DMAB
#undef READA
#undef READB
#undef DOMFMA
}

// ---------------- Kernel 1b: sum K-halves + D-norm + emit swizzled f16 hi/lo rows
// grid (64, 4): block handles [256d][64l] of one image's partial tile.
__global__ __launch_bounds__(256) void norm_split(const float* __restrict__ part,
                                                  char* __restrict__ qemb,
                                                  char* __restrict__ kemb) {
    __shared__ float sm[4][64];
    __shared__ float invn[64];
    __shared__ char stage[64][1040];    // 16B-aligned stride, bank-offset 4/row

    int iid = blockIdx.y;
    int bx  = blockIdx.x;               // 0..63
    int lt  = bx >> 1, lh2 = bx & 1;
    const float* p0 = part + (((size_t)iid * 32 + lt) * 2 + 0) * 32768 + lh2 * 64;
    const float* p1 = p0 + 32768;
    int t = threadIdx.x;
    int ll = t & 63, dq = t >> 6;       // l-local 0..63, d-quarter 0..3

    // phase 1: sum of squares over d
    float sq = 0.f;
    for (int dd = 0; dd < 64; ++dd) {
        int d = dq * 64 + dd;
        float v = p0[d * 128 + ll] + p1[d * 128 + ll];
        sq += v * v;
    }
    sm[dq][ll] = sq;
    __syncthreads();
    if (t < 64) {
        float s = sm[0][t] + sm[1][t] + sm[2][t] + sm[3][t];
        invn[t] = 1.0f / fmaxf(sqrtf(s), 1e-12f);
    }
    __syncthreads();

    // phase 2: scale + split to f16 hi/lo, build swizzled row bytes in LDS
    float sc = invn[ll];
    int swb = (ll & 7) << 4;            // (l&7) == (ll&7): l = lt*128 + lh2*64 + ll
    for (int oc = 0; oc < 8; ++oc) {
        int d0 = dq * 64 + oc * 8;
        f16x8 h8, l8;
#pragma unroll
        for (int j = 0; j < 8; ++j) {
            int d = d0 + j;
            float v = (p0[d * 128 + ll] + p1[d * 128 + ll]) * sc;
            half_t h = (half_t)v;
            h8[j] = h;
            l8[j] = (half_t)(v - (float)h);
        }
        int itb = d0 >> 5;
        int fsc = (d0 >> 3) & 3;
        *(f16x8*)&stage[ll][itb * 128 + ((fsc * 16) ^ swb)] = h8;
        *(f16x8*)&stage[ll][itb * 128 + ((64 + fsc * 16) ^ swb)] = l8;
    }
    __syncthreads();

    // dump 64 rows x 1024B to emb
    int b = iid & 1, type = iid >> 1;
    char* e = (type ? kemb : qemb);
    int rr = t >> 2, c0 = t & 3;
    char* erow = e + ((size_t)b * LL + lt * 128 + lh2 * 64 + rr) * 1024;
    const char* srow = &stage[rr][0];
#pragma unroll
    for (int c = 0; c < 16; ++c) {
        int cj = c0 + c * 4;
        *(float4*)(erow + cj * 16) = *(const float4*)(srow + cj * 16);
    }
}

// ---------------- Kernel 2: zero init (packed max buffer + zero page)
__global__ void init_packed(unsigned long long* p, int n) {
    int i = blockIdx.x * 256 + threadIdx.x;
    if (i < n) p[i] = 0ull;
}

// ---------------- Kernel 3: corr via LDS-staged split-3 MFMA + fused max/argmax
__global__ __launch_bounds__(256, 2) void corr_max_mfma(const char* __restrict__ kemb,
                                                        const char* __restrict__ qemb,
                                                        unsigned long long* __restrict__ packed) {
    __shared__ char sA[2][16384];
    __shared__ char sBq[2][16384];

    int b  = blockIdx.z;
    int l0 = blockIdx.y * 128;
    int m0 = blockIdx.x * 128;
    int t  = threadIdx.x;
    int w = t >> 6, lane = t & 63;
    int wr = w >> 1, wc = w & 1;
    int fr = lane & 15, fs = lane >> 4;

    const char* Abase = kemb + ((size_t)b * LL + l0) * 1024;
    const char* Bbase = qemb + ((size_t)b * LL + m0) * 1024;

    f32x4 acc[4][4];
#pragma unroll
    for (int i = 0; i < 4; i++)
#pragma unroll
        for (int j = 0; j < 4; j++) acc[i][j] = (f32x4){0.f, 0.f, 0.f, 0.f};

#define DMA2(bufi, itv)                                                   \
    do {                                                                  \
        _Pragma("unroll")                                                 \
        for (int c = 0; c < 4; c++) {                                     \
            int idx = c * 4096 + t * 16;                                  \
            int row = idx >> 7, offb = idx & 127;                         \
            __builtin_amdgcn_global_load_lds(                             \
                (const __attribute__((address_space(1))) void*)(Abase + (size_t)row * 1024 + (itv) * 128 + offb), \
                (__attribute__((address_space(3))) void*)(&sA[bufi][idx]), 16, 0, 0); \
        }                                                                 \
        _Pragma("unroll")                                                 \
        for (int c = 0; c < 4; c++) {                                     \
            int idx = c * 4096 + t * 16;                                  \
            int row = idx >> 7, offb = idx & 127;                         \
            __builtin_amdgcn_global_load_lds(                             \
                (const __attribute__((address_space(1))) void*)(Bbase + (size_t)row * 1024 + (itv) * 128 + offb), \
                (__attribute__((address_space(3))) void*)(&sBq[bufi][idx]), 16, 0, 0); \
        }                                                                 \
    } while (0)

    DMA2(0, 0);

    f16x8 ah[4], al[4], bh[4], bl[4];
    for (int it = 0; it < 8; ++it) {
        asm volatile("s_waitcnt vmcnt(0) lgkmcnt(0)" ::: "memory");
        __builtin_amdgcn_s_barrier();
        __builtin_amdgcn_sched_barrier(0);
        if (it < 7) DMA2((it + 1) & 1, it + 1);
        __builtin_amdgcn_sched_barrier(0);
        const char* sa = sA[it & 1];
        const char* sb = sBq[it & 1];
#pragma unroll
        for (int rg = 0; rg < 4; rg++) {
            int r = wr * 64 + rg * 16 + fr;
            const char* rp = sa + r * 128;
            int sw_ = (r & 7) << 4;
            ah[rg] = *(const f16x8*)(rp + ((fs * 16) ^ sw_));
            al[rg] = *(const f16x8*)(rp + ((64 + fs * 16) ^ sw_));
        }
#pragma unroll
        for (int cg = 0; cg < 4; cg++) {
            int r = wc * 64 + cg * 16 + fr;
            const char* rp = sb + r * 128;
            int sw_ = (r & 7) << 4;
            bh[cg] = *(const f16x8*)(rp + ((fs * 16) ^ sw_));
            bl[cg] = *(const f16x8*)(rp + ((64 + fs * 16) ^ sw_));
        }
#pragma unroll
        for (int rg = 0; rg < 4; rg++)
#pragma unroll
            for (int cg = 0; cg < 4; cg++)
                acc[rg][cg] = __builtin_amdgcn_mfma_f32_16x16x32_f16(ah[rg], bh[cg], acc[rg][cg], 0, 0, 0);
#pragma unroll
        for (int rg = 0; rg < 4; rg++)
#pragma unroll
            for (int cg = 0; cg < 4; cg++) {
                acc[rg][cg] = __builtin_amdgcn_mfma_f32_16x16x32_f16(ah[rg], bl[cg], acc[rg][cg], 0, 0, 0);
                acc[rg][cg] = __builtin_amdgcn_mfma_f32_16x16x32_f16(al[rg], bh[cg], acc[rg][cg], 0, 0, 0);
            }
    }
#undef DMA2

#pragma unroll
    for (int cg = 0; cg < 4; cg++) {
        unsigned long long best = 0ull;
#pragma unroll
        for (int rg = 0; rg < 4; rg++) {
#pragma unroll
            for (int r = 0; r < 4; r++) {
                unsigned u = __float_as_uint(acc[rg][cg][r]);
                u = (u & 0x80000000u) ? ~u : (u | 0x80000000u);
                int l = l0 + wr * 64 + rg * 16 + fs * 4 + r;
                unsigned long long p = ((unsigned long long)u << 32) | (unsigned)(4095 - l);
                best = (p > best) ? p : best;
            }
        }
        unsigned long long oo;
        oo = __shfl_xor(best, 16); best = (oo > best) ? oo : best;
        oo = __shfl_xor(best, 32); best = (oo > best) ? oo : best;
        if (lane < 16)
            atomicMax(&packed[(size_t)b * LL + m0 + wc * 64 + cg * 16 + lane], best);
    }
}

// ---------------- Kernel 4: decode packed -> S (d_out) + argmax (ws)
__global__ void decode_packed(const unsigned long long* __restrict__ packed,
                              float* __restrict__ S_out, int* __restrict__ arg) {
    int i = blockIdx.x * 256 + threadIdx.x;
    if (i < BB * LL) {
        unsigned long long p = packed[i];
        unsigned u = (unsigned)(p >> 32);
        unsigned bits = (u & 0x80000000u) ? (u & 0x7FFFFFFFu) : ~u;
        S_out[i] = __uint_as_float(bits);
        arg[i] = 4095 - (int)(unsigned)(p & 0xFFFFFFFFull);
    }
}

// ---------------- Kernel 5/7: batched 2D transpose src[R][Cc] -> dst[Cc][R]
__global__ __launch_bounds__(256) void transpose_mat(const float* __restrict__ src,
                                                     float* __restrict__ dst,
                                                     int R, int Cc) {
    __shared__ float tile[32][33];
    size_t boff = (size_t)blockIdx.z * R * Cc;
    int bx = blockIdx.x;
    int by = blockIdx.y;
    int tx = threadIdx.x & 31;
    int ty = threadIdx.x >> 5;
    const float* s = src + boff;
    float* d = dst + boff;
#pragma unroll
    for (int i = 0; i < 4; i++) {
        int r = by * 32 + ty + i * 8;
        int c = bx * 32 + tx;
        tile[ty + i * 8][tx] = s[(size_t)r * Cc + c];
    }
    __syncthreads();
#pragma unroll
    for (int i = 0; i < 4; i++) {
        int c = bx * 32 + ty + i * 8;
        int r = by * 32 + tx;
        d[(size_t)c * R + r] = tile[tx][ty + i * 8];
    }
}

// ---------------- Kernel 6: gather + fold (channel-last), one pixel per block
__global__ __launch_bounds__(256) void gather_fold(const float* __restrict__ value_t,
                                                   const int* __restrict__ arg,
                                                   float* __restrict__ T_t) {
    int b = blockIdx.y;
    int pix = blockIdx.x;
    int y = pix >> 6, x = pix & 63;
    int t = threadIdx.x;
    float2 acc = make_float2(0.f, 0.f);
    int cnty = (y == 0 || y == HH - 1) ? 2 : 3;
    int cntx = (x == 0 || x == WW - 1) ? 2 : 3;
    const int* ab = arg + b * LL;
    const float* vb = value_t + (size_t)b * LL * CC;
#pragma unroll
    for (int di = 0; di < 3; di++) {
        int my = y + 1 - di;
        if (my < 0 || my >= HH) continue;
#pragma unroll
        for (int dj = 0; dj < 3; dj++) {
            int mx = x + 1 - dj;
            if (mx < 0 || mx >= WW) continue;
            int a = ab[my * WW + mx];
            int ay = a >> 6, ax = a & 63;
            int vy = ay + di - 1, vx = ax + dj - 1;
            if (vy < 0 || vy >= HH || vx < 0 || vx >= WW) continue;
            float2 v = *(const float2*)&vb[((size_t)(vy * WW + vx)) * CC + t * 2];
            acc.x += v.x; acc.y += v.y;
        }
    }
    float inv = 1.0f / (float)(cnty * cntx);
    acc.x *= inv; acc.y *= inv;
    *(float2*)&T_t[((size_t)b * LL + pix) * CC + t * 2] = acc;
}

extern "C" void kernel_launch(void* const* d_in, const int* in_sizes, int n_in,
                              void* d_out, int out_size, void* d_ws, size_t ws_size,
                              hipStream_t stream) {
    const float* query = (const float*)d_in[0];
    const float* key   = (const float*)d_in[1];
    const float* value = (const float*)d_in[2];
    const float* Wemb  = (const float*)d_in[3];

    float* out   = (float*)d_out;
    float* S_out = out;
    float* T_out = out + BB * LL;

    char* ws = (char*)d_ws;
    // layout (~88.7 MB):
    char*  img_ts = ws;                                  // 33,554,432 (dead after embed)
    char*  Wst    = ws + 33554432;                       //  4,718,592 (dead after embed)
    float* part   = (float*)(ws + 38273024);             // 33,554,432 (dead after norm_split)
    char*  qemb   = ws + 71827456;                       //  8,388,608 (dead after corr)
    char*  kemb   = ws + 80216064;                       //  8,388,608 (dead after corr)
    unsigned long long* packed = (unsigned long long*)(ws + 88604672);  // 65,536
    char*  zp     = ws + 88670208;                       //  4,096 (zeroed page)
    int*   arg    = (int*)(ws + 88674304);               // 32,768
    float* val_t  = (float*)(ws + 38273024);             // alias part[0:16.78MB]
    float* T_t    = (float*)(ws + 38273024 + 16777216);  // alias part[16.78:33.55MB]

    init_packed   <<<dim3(34), 256, 0, stream>>>(packed, 8704);  // packed + zp
    presplit      <<<dim3(64, 4), 256, 0, stream>>>(query, key, img_ts);
    splitW2b      <<<dim3(576), 256, 0, stream>>>(Wemb, Wst);
    embed_mfma    <<<dim3(32, 4, 2), 512, 0, stream>>>(img_ts, Wst, zp, part);
    norm_split    <<<dim3(64, 4), 256, 0, stream>>>(part, qemb, kemb);
    corr_max_mfma <<<dim3(32, 32, 2), 256, 0, stream>>>(kemb, qemb, packed);
    decode_packed <<<dim3(32), 256, 0, stream>>>(packed, S_out, arg);
    transpose_mat <<<dim3(128, 16, 2), 256, 0, stream>>>(value, val_t, CC, LL);
    gather_fold   <<<dim3(4096, 2), 256, 0, stream>>>(val_t, arg, T_t);
    transpose_mat <<<dim3(16, 128, 2), 256, 0, stream>>>(T_t, T_out, LL, CC);
}